// Round 4
// baseline (442.438 us; speedup 1.0000x reference)
//
#include <hip/hip_runtime.h>
#include <climits>

// ---------------------------------------------------------------------------
// RelativeMultiHeadAttentionBlock (Transformer-XL style) on MI355X (gfx950)
// B=2, T=C=1024, M=1024, S=2048, H=16, HD=64, F=1024. fp32 in/out, bf16 MFMA.
//
// R3: attn concurrency-first:
//  - 4-way key split: chunk = wave id in block; 8192 independent waves,
//    2048 blocks (8/CU), 4 waves/block with NO barriers, 8KB LDS/block.
//  - r-fragment carry across jt (band slides 16 rows): 16->10 r loads/tile.
//  - K/V/r direct from L2 (XCD remap: 4 bh per XCD). P via 2KB wave-private
//    LDS round trip.
//  - pO partials (16MB) overlay [0,16MB) of ws (xbf/relbf/qkvr-weights dead
//    by attn time; wo^T lives at W+16MB).
// ---------------------------------------------------------------------------

typedef unsigned short u16;
typedef short bf16x8 __attribute__((ext_vector_type(8)));
typedef float f32x4 __attribute__((ext_vector_type(4)));

__device__ __forceinline__ f32x4 mfma16x16x32(bf16x8 a, bf16x8 b, f32x4 c) {
  return __builtin_amdgcn_mfma_f32_16x16x32_bf16(a, b, c, 0, 0, 0);
}

__device__ __forceinline__ u16 f2bf(float f) {  // RNE f32->bf16
  unsigned u = __builtin_bit_cast(unsigned, f);
  u = (u + 0x7FFFu + ((u >> 16) & 1u)) >> 16;
  return (u16)u;
}

__device__ __forceinline__ float bf2f(u16 x) {
  unsigned u = ((unsigned)x) << 16;
  return __builtin_bit_cast(float, u);
}

__device__ __forceinline__ void gll16(const void* g, void* l) {
  __builtin_amdgcn_global_load_lds(
      (const __attribute__((address_space(1))) void*)g,
      (__attribute__((address_space(3))) void*)l, 16, 0, 0);
}

// --- segment ids ------------------------------------------------------------
__global__ __launch_bounds__(64) void seg_scan_kernel(
    const int* __restrict__ mask, const int* __restrict__ mem_mask,
    const int* __restrict__ cache_mask, int* __restrict__ qseg,
    int* __restrict__ kseg) {
  __shared__ int cs[3072];
  int b = blockIdx.x, lane = threadIdx.x;
  int carry = 0;
  for (int base = 0; base < 3072; base += 64) {
    int idx = base + lane;
    int val;
    if (idx < 1024)      val = mem_mask[b * 1024 + idx];
    else if (idx < 2048) val = cache_mask[b * 1024 + idx - 1024];
    else                 val = mask[b * 1024 + idx - 2048];
    for (int o = 1; o < 64; o <<= 1) {
      int n = __shfl_up(val, o);
      if (lane >= o) val += n;
    }
    val += carry;
    cs[idx] = val;
    carry = __shfl(val, 63);
  }
  __syncthreads();
  int mx = INT_MIN;
  for (int i = lane; i < 2048; i += 64) mx = max(mx, cs[i]);
  for (int o = 1; o < 64; o <<= 1) mx = max(mx, __shfl_xor(mx, o));
  int cs2047 = cs[2047];
  for (int t = lane; t < 1024; t += 64) qseg[b * 1024 + t] = cs[2048 + t] - cs2047 + mx;
  for (int j = lane; j < 2048; j += 64) kseg[b * 2048 + j] = cs[1024 + j];
}

// --- preps ------------------------------------------------------------------
__global__ __launch_bounds__(256) void cvt_bf16_kernel(const float* __restrict__ src,
                                                       u16* __restrict__ dst, int n) {
  int i = (blockIdx.x * 256 + threadIdx.x) * 4;
  if (i >= n) return;
  float4 v = *(const float4*)(src + i);
  dst[i + 0] = f2bf(v.x); dst[i + 1] = f2bf(v.y);
  dst[i + 2] = f2bf(v.z); dst[i + 3] = f2bf(v.w);
}

__global__ __launch_bounds__(256) void tr_w_kernel(const float* __restrict__ src,
                                                   u16* __restrict__ dst) {
  __shared__ float tile[32][33];
  int tx = threadIdx.x & 31, ty = threadIdx.x >> 5;
  int r0 = blockIdx.y * 32, c0 = blockIdx.x * 32;
#pragma unroll
  for (int i = 0; i < 32; i += 8)
    tile[ty + i][tx] = src[(size_t)(r0 + ty + i) * 1024 + c0 + tx];
  __syncthreads();
#pragma unroll
  for (int i = 0; i < 32; i += 8)
    dst[(size_t)(c0 + ty + i) * 1024 + r0 + tx] = f2bf(tile[tx][ty + i]);
}

__global__ __launch_bounds__(256) void ck_perm_kernel(const float* __restrict__ src,
                                                      u16* __restrict__ dst) {
  int i = blockIdx.x * 256 + threadIdx.x;  // 524288 quads
  int dq = i & 15, h = (i >> 4) & 15, t = (i >> 8) & 1023, b = i >> 18;
  float4 v = *(const float4*)(src + (size_t)i * 4);
  size_t o = (((size_t)(b * 16 + h)) * 2048 + t) * 64 + dq * 4;
  dst[o + 0] = f2bf(v.x); dst[o + 1] = f2bf(v.y);
  dst[o + 2] = f2bf(v.z); dst[o + 3] = f2bf(v.w);
}

__global__ __launch_bounds__(256) void cv_tr_kernel(const float* __restrict__ src,
                                                    u16* __restrict__ dst) {
  __shared__ float tile[32][33];
  int bh = blockIdx.z, b = bh >> 4, h = bh & 15;
  int t0 = blockIdx.x * 32, d0 = blockIdx.y * 32;
  int tx = threadIdx.x & 31, ty = threadIdx.x >> 5;
#pragma unroll
  for (int i = 0; i < 32; i += 8)
    tile[ty + i][tx] = src[(((size_t)b * 1024 + t0 + ty + i) * 16 + h) * 64 + d0 + tx];
  __syncthreads();
#pragma unroll
  for (int i = 0; i < 32; i += 8)
    dst[((size_t)bh * 64 + d0 + ty + i) * 2048 + t0 + tx] = f2bf(tile[tx][ty + i]);
}

// --- projection / output GEMM ----------------------------------------------
__global__ __launch_bounds__(256) void gemm_proj_kernel(
    const u16* __restrict__ xbf, const u16* __restrict__ relbf,
    const u16* __restrict__ obf, const u16* __restrict__ wt5,
    u16* __restrict__ qu, u16* __restrict__ qv, u16* __restrict__ kbuf,
    u16* __restrict__ vtbuf, u16* __restrict__ rbuf, float* __restrict__ dout,
    const float* __restrict__ uvec, const float* __restrict__ vvec, int movr) {
  __shared__ __align__(16) u16 lA[64 * 64];
  __shared__ __align__(16) u16 lB[64 * 64];
  const int mode = (movr >= 0) ? movr : (int)blockIdx.z;
  const u16* A = (mode == 3) ? relbf : ((mode == 4) ? obf : xbf);
  const u16* Wm = wt5 + (size_t)mode * 1048576;
  const int tid = threadIdx.x;
  const int lane = tid & 63, gq = lane >> 4, cl = lane & 15;
  const int wv = tid >> 6, wm = wv >> 1, wn = wv & 1;
  const int by = blockIdx.y * 64, bx = blockIdx.x * 64;
  const f32x4 fz = {0.f, 0.f, 0.f, 0.f};

  f32x4 acc[2][2];
#pragma unroll
  for (int a = 0; a < 2; ++a)
#pragma unroll
    for (int bq = 0; bq < 2; ++bq) acc[a][bq] = fz;

  const int off0 = tid * 16, off1 = tid * 16 + 4096;
  const int L0 = off0 ^ (((off0 >> 7) & 7) << 4);
  const int L1 = off1 ^ (((off1 >> 7) & 7) << 4);
  const int rr0 = off0 >> 7, ke0 = (L0 & 127) >> 1;
  const int rr1 = off1 >> 7, ke1 = (L1 & 127) >> 1;
  const u16* pA0 = A + (size_t)(by + rr0) * 1024 + ke0;
  const u16* pA1 = A + (size_t)(by + rr1) * 1024 + ke1;
  const u16* pB0 = Wm + (size_t)(bx + rr0) * 1024 + ke0;
  const u16* pB1 = Wm + (size_t)(bx + rr1) * 1024 + ke1;

  for (int k0 = 0; k0 < 1024; k0 += 64) {
    gll16(pA0 + k0, (char*)lA + off0);
    gll16(pA1 + k0, (char*)lA + off1);
    gll16(pB0 + k0, (char*)lB + off0);
    gll16(pB1 + k0, (char*)lB + off1);
    __syncthreads();
    bf16x8 af[2][2], bff[2][2];
#pragma unroll
    for (int mi = 0; mi < 2; ++mi)
#pragma unroll
      for (int kb = 0; kb < 2; ++kb) {
        int row = wm * 32 + mi * 16 + cl;
        int byte = row * 128 + kb * 64 + gq * 16;
        byte ^= ((row & 7) << 4);
        af[mi][kb] = *(const bf16x8*)((const char*)lA + byte);
      }
#pragma unroll
    for (int ni = 0; ni < 2; ++ni)
#pragma unroll
      for (int kb = 0; kb < 2; ++kb) {
        int row = wn * 32 + ni * 16 + cl;
        int byte = row * 128 + kb * 64 + gq * 16;
        byte ^= ((row & 7) << 4);
        bff[ni][kb] = *(const bf16x8*)((const char*)lB + byte);
      }
#pragma unroll
    for (int mi = 0; mi < 2; ++mi)
#pragma unroll
      for (int ni = 0; ni < 2; ++ni) {
        acc[mi][ni] = mfma16x16x32(af[mi][0], bff[ni][0], acc[mi][ni]);
        acc[mi][ni] = mfma16x16x32(af[mi][1], bff[ni][1], acc[mi][ni]);
      }
    __syncthreads();
  }

#pragma unroll
  for (int mi = 0; mi < 2; ++mi)
#pragma unroll
    for (int ni = 0; ni < 2; ++ni) {
      int n = bx + wn * 32 + ni * 16 + cl;
      float ub = 0.f, vb = 0.f;
      if (mode == 0) { ub = uvec[n]; vb = vvec[n]; }
#pragma unroll
      for (int r = 0; r < 4; ++r) {
        int m = by + wm * 32 + mi * 16 + 4 * gq + r;
        float val = acc[mi][ni][r];
        if (mode == 0) {
          // softmax scale (1/8) folded in here
          qu[(size_t)m * 1024 + n] = f2bf((val + ub) * 0.125f);
          qv[(size_t)m * 1024 + n] = f2bf((val + vb) * 0.125f);
        } else if (mode == 1) {
          dout[2097152 + (size_t)m * 1024 + n] = val;
          kbuf[(((size_t)((m >> 10) * 16 + (n >> 6))) * 2048 + 1024 + (m & 1023)) * 64 +
               (n & 63)] = f2bf(val);
        } else if (mode == 2) {
          dout[4194304 + (size_t)m * 1024 + n] = val;
          vtbuf[(((size_t)((m >> 10) * 16 + (n >> 6))) * 64 + (n & 63)) * 2048 + 1024 +
                (m & 1023)] = f2bf(val);
        } else if (mode == 3) {
          rbuf[((size_t)(n >> 6) * 2048 + m) * 64 + (n & 63)] = f2bf(val);
        } else {
          dout[(size_t)m * 1024 + n] = val;
        }
      }
    }
}

// --- flash attention, 4-way split-key, 4 independent waves per block --------
// grid (64, 32): lin -> XCD remap -> (bh, qt); wave wv = key chunk 0..3.
__global__ __launch_bounds__(256, 6) void attn_kernel(
    const u16* __restrict__ qu, const u16* __restrict__ qv,
    const u16* __restrict__ kbuf, const u16* __restrict__ vtbuf,
    const u16* __restrict__ rbuf, const int* __restrict__ qseg,
    const int* __restrict__ kseg, u16* __restrict__ pO,
    float* __restrict__ pml) {
  __shared__ __align__(16) u16 ldsP[4][16 * 64];  // 2KB per wave, private

  const int tid = threadIdx.x, lane = tid & 63;
  const int gq = lane >> 4, cl = lane & 15;
  const int wv = tid >> 6;  // = key chunk
  // XCD-locality remap (bijective over 2048): 4 bh per XCD
  int lin = blockIdx.x + 64 * blockIdx.y;
  lin = (lin & 7) * 256 + (lin >> 3);
  const int bh = lin >> 6, qt = lin & 63;
  const int chunk = wv;
  const int b = bh >> 4, h = bh & 15;
  const int i0 = qt * 16;
  const int tmax = (i0 + 15 + 1024) >> 6;
  const f32x4 fz = {0.f, 0.f, 0.f, 0.f};

  const u16* Kb = kbuf + (size_t)bh * 2048 * 64;   // [s][d=64]
  const u16* Vb = vtbuf + (size_t)bh * 64 * 2048;  // [d][s=2048]
  const u16* rbh = rbuf + (size_t)h * 2048 * 64;   // [e][d=64]

  // Q fragments (pre-scaled by 1/8): row=cl, k=32*kb+8*gq+j
  bf16x8 aU[2], aV[2];
#pragma unroll
  for (int kb = 0; kb < 2; ++kb) {
    size_t off = ((size_t)b * 1024 + i0 + cl) * 1024 + h * 64 + kb * 32 + gq * 8;
    aU[kb] = *(const bf16x8*)(qu + off);
    aV[kb] = *(const bf16x8*)(qv + off);
  }
  int qsv[4];
#pragma unroll
  for (int r = 0; r < 4; ++r) qsv[r] = qseg[b * 1024 + i0 + 4 * gq + r];

  float mrun[4], lrun[4];
  f32x4 oacc[4];
#pragma unroll
  for (int r = 0; r < 4; ++r) { mrun[r] = -1e30f; lrun[r] = 0.f; }
#pragma unroll
  for (int di = 0; di < 4; ++di) oacc[di] = fz;

  for (int t = chunk; t <= tmax; t += 4) {
    const int j0t = t * 64;
    const int Rb0 = j0t - i0 + 1008;  // 16-aligned band base, >= 0
    // initial r rows (Rb0+cl), both d-halves; carried across jt
    const u16* rpA = rbh + (size_t)min(Rb0 + cl, 2047) * 64 + gq * 8;
    bf16x8 rA0 = *(const bf16x8*)(rpA);
    bf16x8 rA1 = *(const bf16x8*)(rpA + 32);
    float x[4][4];
#pragma unroll
    for (int jt = 0; jt < 4; ++jt) {
      int j0 = j0t + jt * 16;
      const u16* kp = Kb + (size_t)(j0 + cl) * 64 + gq * 8;
      bf16x8 k0 = *(const bf16x8*)kp;
      bf16x8 k1 = *(const bf16x8*)(kp + 32);
      f32x4 xq = mfma16x16x32(aU[0], k0, fz);
      xq = mfma16x16x32(aU[1], k1, xq);
      const u16* rpB = rbh + (size_t)min(Rb0 + 16 * jt + 16 + cl, 2047) * 64 + gq * 8;
      bf16x8 rB0 = *(const bf16x8*)(rpB);
      bf16x8 rB1 = *(const bf16x8*)(rpB + 32);
      f32x4 b0 = mfma16x16x32(aV[0], rA0, fz);
      b0 = mfma16x16x32(aV[1], rA1, b0);
      f32x4 b1 = mfma16x16x32(aV[0], rB0, fz);
      b1 = mfma16x16x32(aV[1], rB1, b1);
      rA0 = rB0; rA1 = rB1;  // carry: next jt's low band = this high band
      int ksv = kseg[(size_t)b * 2048 + j0 + cl];
#pragma unroll
      for (int r = 0; r < 4; ++r) {
        int ri = 4 * gq + r;
        int lc = cl - ri + 15;  // in [0,30]
        int srcl = (gq << 4) | (lc & 15);
        float d0 = __shfl(b0[r], srcl);
        float d1 = __shfl(b1[r], srcl);
        float bdv = (lc < 16) ? d0 : d1;
        int j = j0 + cl;
        bool ok = (j <= i0 + ri + 1024) && (ksv == qsv[r]);
        x[jt][r] = ok ? (xq[r] + bdv) : -1e30f;
      }
    }
    // online softmax over 64 keys (row spread over 16 lanes x 4 jt)
    char* Pm = (char*)ldsP[wv];
    float alf[4];
#pragma unroll
    for (int r = 0; r < 4; ++r) {
      float mx = fmaxf(fmaxf(x[0][r], x[1][r]), fmaxf(x[2][r], x[3][r]));
      mx = fmaxf(mx, __shfl_xor(mx, 1));
      mx = fmaxf(mx, __shfl_xor(mx, 2));
      mx = fmaxf(mx, __shfl_xor(mx, 4));
      mx = fmaxf(mx, __shfl_xor(mx, 8));
      float mold = mrun[r];
      float mnew = fmaxf(mold, mx);
      float al = __expf(mold - mnew);
      float p0 = __expf(x[0][r] - mnew);
      float p1 = __expf(x[1][r] - mnew);
      float p2 = __expf(x[2][r] - mnew);
      float p3 = __expf(x[3][r] - mnew);
      float s = p0 + p1 + p2 + p3;
      s += __shfl_xor(s, 1); s += __shfl_xor(s, 2);
      s += __shfl_xor(s, 4); s += __shfl_xor(s, 8);
      mrun[r] = mnew;
      lrun[r] = lrun[r] * al + s;
      alf[r] = al;
      int ri = 4 * gq + r;
      int bb = (ri & 7) << 4;
      *(u16*)(Pm + ((ri * 128 + cl * 2) ^ bb)) = f2bf(p0);
      *(u16*)(Pm + ((ri * 128 + (16 + cl) * 2) ^ bb)) = f2bf(p1);
      *(u16*)(Pm + ((ri * 128 + (32 + cl) * 2) ^ bb)) = f2bf(p2);
      *(u16*)(Pm + ((ri * 128 + (48 + cl) * 2) ^ bb)) = f2bf(p3);
    }
    f32x4 av = {alf[0], alf[1], alf[2], alf[3]};
#pragma unroll
    for (int di = 0; di < 4; ++di) oacc[di] *= av;
    // PV: P round-trip (same wave; compiler orders lgkmcnt), V direct from L2
    int psw = (cl & 7) << 4;
    bf16x8 pf0 = *(const bf16x8*)(Pm + ((cl * 128 + gq * 16) ^ psw));
    bf16x8 pf1 = *(const bf16x8*)(Pm + ((cl * 128 + 64 + gq * 16) ^ psw));
#pragma unroll
    for (int di = 0; di < 4; ++di) {
      const u16* vp = Vb + (size_t)(di * 16 + cl) * 2048 + j0t + gq * 8;
      bf16x8 v0 = *(const bf16x8*)(vp);
      bf16x8 v1 = *(const bf16x8*)(vp + 32);
      oacc[di] = mfma16x16x32(pf0, v0, oacc[di]);
      oacc[di] = mfma16x16x32(pf1, v1, oacc[di]);
    }
  }

  // epilogue: raw partials (no 1/l) + (m,l)
#pragma unroll
  for (int r = 0; r < 4; ++r) {
    int iq = i0 + 4 * gq + r;
    size_t rowp = ((size_t)bh * 4 + chunk) * 1024 + iq;
#pragma unroll
    for (int di = 0; di < 4; ++di)
      pO[rowp * 64 + di * 16 + cl] = f2bf(oacc[di][r]);
    if (cl == 0) {
      pml[rowp * 2] = mrun[r];
      pml[rowp * 2 + 1] = lrun[r];
    }
  }
}

// --- split-key combine (4 chunks) -------------------------------------------
__global__ __launch_bounds__(256) void combine_kernel(
    const u16* __restrict__ pO, const float* __restrict__ pml,
    u16* __restrict__ obf) {
  int gid = blockIdx.x * 256 + threadIdx.x;  // 262144
  int d8 = (gid & 7) * 8;
  int row = gid >> 3;  // bh*1024 + iq
  int bh = row >> 10, iq = row & 1023;
  int b = bh >> 4, h = bh & 15;
  size_t rbase = (size_t)bh * 4 * 1024 + iq;
  float m[4], l[4], w[4];
  float ms = -1e30f;
#pragma unroll
  for (int c = 0; c < 4; ++c) {
    m[c] = pml[(rbase + c * 1024) * 2];
    l[c] = pml[(rbase + c * 1024) * 2 + 1];
    ms = fmaxf(ms, m[c]);
  }
  float den = 0.f;
#pragma unroll
  for (int c = 0; c < 4; ++c) { w[c] = __expf(m[c] - ms); den += l[c] * w[c]; }
  float inv = 1.0f / fmaxf(den, 1e-30f);
  float acc[8] = {0, 0, 0, 0, 0, 0, 0, 0};
#pragma unroll
  for (int c = 0; c < 4; ++c) {
    bf16x8 a = *(const bf16x8*)(pO + (rbase + c * 1024) * 64 + d8);
#pragma unroll
    for (int j = 0; j < 8; ++j) acc[j] += bf2f((u16)a[j]) * w[c];
  }
  bf16x8 o;
#pragma unroll
  for (int j = 0; j < 8; ++j) o[j] = (short)f2bf(acc[j] * inv);
  *(bf16x8*)(obf + ((size_t)b * 1024 + iq) * 1024 + h * 64 + d8) = o;
}

// ---------------------------------------------------------------------------
extern "C" void kernel_launch(void* const* d_in, const int* in_sizes, int n_in,
                              void* d_out, int out_size, void* d_ws, size_t ws_size,
                              hipStream_t stream) {
  (void)in_sizes; (void)n_in; (void)out_size; (void)ws_size;
  const float* x           = (const float*)d_in[0];
  const int*   mask        = (const int*)d_in[1];
  const int*   mem_mask    = (const int*)d_in[3];
  const float* cache_key   = (const float*)d_in[4];
  const float* cache_value = (const float*)d_in[5];
  const int*   cache_mask  = (const int*)d_in[6];
  const float* rel_emb     = (const float*)d_in[7];
  const float* Wq          = (const float*)d_in[8];
  const float* Wk          = (const float*)d_in[9];
  const float* Wv          = (const float*)d_in[10];
  const float* Wr          = (const float*)d_in[11];
  const float* uvec        = (const float*)d_in[12];
  const float* vvec        = (const float*)d_in[13];
  const float* Wo          = (const float*)d_in[14];
  float* dout = (float*)d_out;

  char* W = (char*)d_ws;  // ~51.1 MB of workspace used
  u16* xbf   = (u16*)(W + (0u << 20));   // dead after projection GEMMs
  u16* relbf = (u16*)(W + (4u << 20));   // dead after projection GEMMs
  u16* pO    = (u16*)(W + (0u << 20));   // 16MB: overlays xbf,relbf,qkvr wts
  u16* wt5   = (u16*)(W + (8u << 20));   // q,k,v,r (dead by attn), o at +8MB
  u16* kbuf  = (u16*)(W + (18u << 20));
  u16* vtbuf = (u16*)(W + (26u << 20));
  u16* rbuf  = (u16*)(W + (34u << 20));
  u16* qu    = (u16*)(W + (38u << 20));
  u16* qv    = (u16*)(W + (42u << 20));
  u16* obf   = (u16*)(W + (46u << 20));
  int* qseg  = (int*)(W + (50u << 20));
  int* kseg  = (int*)(W + (50u << 20) + 8192);
  float* pml = (float*)(W + (50u << 20) + 32768);

  seg_scan_kernel<<<dim3(2), dim3(64), 0, stream>>>(mask, mem_mask, cache_mask, qseg, kseg);
  cvt_bf16_kernel<<<dim3(2048), dim3(256), 0, stream>>>(x, xbf, 2097152);
  cvt_bf16_kernel<<<dim3(2048), dim3(256), 0, stream>>>(rel_emb, relbf, 2097152);
  tr_w_kernel<<<dim3(32, 32), dim3(256), 0, stream>>>(Wq, wt5);
  tr_w_kernel<<<dim3(32, 32), dim3(256), 0, stream>>>(Wk, wt5 + (1u << 20));
  tr_w_kernel<<<dim3(32, 32), dim3(256), 0, stream>>>(Wv, wt5 + (2u << 20));
  tr_w_kernel<<<dim3(32, 32), dim3(256), 0, stream>>>(Wr, wt5 + (3u << 20));
  tr_w_kernel<<<dim3(32, 32), dim3(256), 0, stream>>>(Wo, wt5 + (4u << 20));
  ck_perm_kernel<<<dim3(2048), dim3(256), 0, stream>>>(cache_key, kbuf);
  cv_tr_kernel<<<dim3(32, 2, 32), dim3(256), 0, stream>>>(cache_value, vtbuf);
  gemm_proj_kernel<<<dim3(16, 32, 4), dim3(256), 0, stream>>>(
      xbf, relbf, obf, wt5, qu, qv, kbuf, vtbuf, rbuf, dout, uvec, vvec, -1);
  attn_kernel<<<dim3(64, 32), dim3(256), 0, stream>>>(qu, qv, kbuf, vtbuf, rbuf,
                                                      qseg, kseg, pO, pml);
  combine_kernel<<<dim3(1024), dim3(256), 0, stream>>>(pO, pml, obf);
  gemm_proj_kernel<<<dim3(16, 32, 1), dim3(256), 0, stream>>>(
      xbf, relbf, obf, wt5, qu, qv, kbuf, vtbuf, rbuf, dout, uvec, vvec, 4);
}

// Round 5
// 287.915 us; speedup vs baseline: 1.5367x; 1.5367x over previous
//
#include <hip/hip_runtime.h>
#include <climits>

// ---------------------------------------------------------------------------
// RelativeMultiHeadAttentionBlock (Transformer-XL style) on MI355X (gfx950)
// B=2, T=C=1024, M=1024, S=2048, H=16, HD=64, F=1024. fp32 in/out, bf16 MFMA.
//
// R4: revert to R2's proven L2-resident shape (1 wave/block, 2-chunk split,
// XCD remap, FETCH ~18MB), then cut the per-tile serial latency chain:
//  - all of a tile's loads batch-issued into registers (one vmcnt drain)
//  - band sharing: bd1[jt] == bd0[jt+1] -> bias mfmas 16->10, gathers 32->20,
//    all independent; srcl/masks hoisted out of the loop
//  - DPP row_ror allreduce (VALU pipe) replaces bpermute softmax reduces
// ---------------------------------------------------------------------------

typedef unsigned short u16;
typedef short bf16x8 __attribute__((ext_vector_type(8)));
typedef float f32x4 __attribute__((ext_vector_type(4)));

__device__ __forceinline__ f32x4 mfma16x16x32(bf16x8 a, bf16x8 b, f32x4 c) {
  return __builtin_amdgcn_mfma_f32_16x16x32_bf16(a, b, c, 0, 0, 0);
}

__device__ __forceinline__ u16 f2bf(float f) {  // RNE f32->bf16
  unsigned u = __builtin_bit_cast(unsigned, f);
  u = (u + 0x7FFFu + ((u >> 16) & 1u)) >> 16;
  return (u16)u;
}

__device__ __forceinline__ float bf2f(u16 x) {
  unsigned u = ((unsigned)x) << 16;
  return __builtin_bit_cast(float, u);
}

__device__ __forceinline__ void gll16(const void* g, void* l) {
  __builtin_amdgcn_global_load_lds(
      (const __attribute__((address_space(1))) void*)g,
      (__attribute__((address_space(3))) void*)l, 16, 0, 0);
}

// DPP 16-lane rotation allreduce (VALU pipe; rows of 16 = our gq groups)
template <int CTRL>
__device__ __forceinline__ float rot16(float x) {
  int i = __builtin_bit_cast(int, x);
  int r = __builtin_amdgcn_update_dpp(i, i, CTRL, 0xF, 0xF, false);
  return __builtin_bit_cast(float, r);
}
__device__ __forceinline__ float dpp_max16(float x) {
  x = fmaxf(x, rot16<0x128>(x));  // ror:8
  x = fmaxf(x, rot16<0x124>(x));  // ror:4
  x = fmaxf(x, rot16<0x122>(x));  // ror:2
  x = fmaxf(x, rot16<0x121>(x));  // ror:1
  return x;
}
__device__ __forceinline__ float dpp_sum16(float x) {
  x += rot16<0x128>(x);
  x += rot16<0x124>(x);
  x += rot16<0x122>(x);
  x += rot16<0x121>(x);
  return x;
}

// --- segment ids ------------------------------------------------------------
__global__ __launch_bounds__(64) void seg_scan_kernel(
    const int* __restrict__ mask, const int* __restrict__ mem_mask,
    const int* __restrict__ cache_mask, int* __restrict__ qseg,
    int* __restrict__ kseg) {
  __shared__ int cs[3072];
  int b = blockIdx.x, lane = threadIdx.x;
  int carry = 0;
  for (int base = 0; base < 3072; base += 64) {
    int idx = base + lane;
    int val;
    if (idx < 1024)      val = mem_mask[b * 1024 + idx];
    else if (idx < 2048) val = cache_mask[b * 1024 + idx - 1024];
    else                 val = mask[b * 1024 + idx - 2048];
    for (int o = 1; o < 64; o <<= 1) {
      int n = __shfl_up(val, o);
      if (lane >= o) val += n;
    }
    val += carry;
    cs[idx] = val;
    carry = __shfl(val, 63);
  }
  __syncthreads();
  int mx = INT_MIN;
  for (int i = lane; i < 2048; i += 64) mx = max(mx, cs[i]);
  for (int o = 1; o < 64; o <<= 1) mx = max(mx, __shfl_xor(mx, o));
  int cs2047 = cs[2047];
  for (int t = lane; t < 1024; t += 64) qseg[b * 1024 + t] = cs[2048 + t] - cs2047 + mx;
  for (int j = lane; j < 2048; j += 64) kseg[b * 2048 + j] = cs[1024 + j];
}

// --- preps ------------------------------------------------------------------
__global__ __launch_bounds__(256) void cvt_bf16_kernel(const float* __restrict__ src,
                                                       u16* __restrict__ dst, int n) {
  int i = (blockIdx.x * 256 + threadIdx.x) * 4;
  if (i >= n) return;
  float4 v = *(const float4*)(src + i);
  dst[i + 0] = f2bf(v.x); dst[i + 1] = f2bf(v.y);
  dst[i + 2] = f2bf(v.z); dst[i + 3] = f2bf(v.w);
}

__global__ __launch_bounds__(256) void tr_w_kernel(const float* __restrict__ src,
                                                   u16* __restrict__ dst) {
  __shared__ float tile[32][33];
  int tx = threadIdx.x & 31, ty = threadIdx.x >> 5;
  int r0 = blockIdx.y * 32, c0 = blockIdx.x * 32;
#pragma unroll
  for (int i = 0; i < 32; i += 8)
    tile[ty + i][tx] = src[(size_t)(r0 + ty + i) * 1024 + c0 + tx];
  __syncthreads();
#pragma unroll
  for (int i = 0; i < 32; i += 8)
    dst[(size_t)(c0 + ty + i) * 1024 + r0 + tx] = f2bf(tile[tx][ty + i]);
}

__global__ __launch_bounds__(256) void ck_perm_kernel(const float* __restrict__ src,
                                                      u16* __restrict__ dst) {
  int i = blockIdx.x * 256 + threadIdx.x;  // 524288 quads
  int dq = i & 15, h = (i >> 4) & 15, t = (i >> 8) & 1023, b = i >> 18;
  float4 v = *(const float4*)(src + (size_t)i * 4);
  size_t o = (((size_t)(b * 16 + h)) * 2048 + t) * 64 + dq * 4;
  dst[o + 0] = f2bf(v.x); dst[o + 1] = f2bf(v.y);
  dst[o + 2] = f2bf(v.z); dst[o + 3] = f2bf(v.w);
}

__global__ __launch_bounds__(256) void cv_tr_kernel(const float* __restrict__ src,
                                                    u16* __restrict__ dst) {
  __shared__ float tile[32][33];
  int bh = blockIdx.z, b = bh >> 4, h = bh & 15;
  int t0 = blockIdx.x * 32, d0 = blockIdx.y * 32;
  int tx = threadIdx.x & 31, ty = threadIdx.x >> 5;
#pragma unroll
  for (int i = 0; i < 32; i += 8)
    tile[ty + i][tx] = src[(((size_t)b * 1024 + t0 + ty + i) * 16 + h) * 64 + d0 + tx];
  __syncthreads();
#pragma unroll
  for (int i = 0; i < 32; i += 8)
    dst[((size_t)bh * 64 + d0 + ty + i) * 2048 + t0 + tx] = f2bf(tile[tx][ty + i]);
}

// --- projection / output GEMM ----------------------------------------------
__global__ __launch_bounds__(256) void gemm_proj_kernel(
    const u16* __restrict__ xbf, const u16* __restrict__ relbf,
    const u16* __restrict__ obf, const u16* __restrict__ wt5,
    u16* __restrict__ qu, u16* __restrict__ qv, u16* __restrict__ kbuf,
    u16* __restrict__ vtbuf, u16* __restrict__ rbuf, float* __restrict__ dout,
    const float* __restrict__ uvec, const float* __restrict__ vvec, int movr) {
  __shared__ __align__(16) u16 lA[64 * 64];
  __shared__ __align__(16) u16 lB[64 * 64];
  const int mode = (movr >= 0) ? movr : (int)blockIdx.z;
  const u16* A = (mode == 3) ? relbf : ((mode == 4) ? obf : xbf);
  const u16* Wm = wt5 + (size_t)mode * 1048576;
  const int tid = threadIdx.x;
  const int lane = tid & 63, gq = lane >> 4, cl = lane & 15;
  const int wv = tid >> 6, wm = wv >> 1, wn = wv & 1;
  const int by = blockIdx.y * 64, bx = blockIdx.x * 64;
  const f32x4 fz = {0.f, 0.f, 0.f, 0.f};

  f32x4 acc[2][2];
#pragma unroll
  for (int a = 0; a < 2; ++a)
#pragma unroll
    for (int bq = 0; bq < 2; ++bq) acc[a][bq] = fz;

  const int off0 = tid * 16, off1 = tid * 16 + 4096;
  const int L0 = off0 ^ (((off0 >> 7) & 7) << 4);
  const int L1 = off1 ^ (((off1 >> 7) & 7) << 4);
  const int rr0 = off0 >> 7, ke0 = (L0 & 127) >> 1;
  const int rr1 = off1 >> 7, ke1 = (L1 & 127) >> 1;
  const u16* pA0 = A + (size_t)(by + rr0) * 1024 + ke0;
  const u16* pA1 = A + (size_t)(by + rr1) * 1024 + ke1;
  const u16* pB0 = Wm + (size_t)(bx + rr0) * 1024 + ke0;
  const u16* pB1 = Wm + (size_t)(bx + rr1) * 1024 + ke1;

  for (int k0 = 0; k0 < 1024; k0 += 64) {
    gll16(pA0 + k0, (char*)lA + off0);
    gll16(pA1 + k0, (char*)lA + off1);
    gll16(pB0 + k0, (char*)lB + off0);
    gll16(pB1 + k0, (char*)lB + off1);
    __syncthreads();
    bf16x8 af[2][2], bff[2][2];
#pragma unroll
    for (int mi = 0; mi < 2; ++mi)
#pragma unroll
      for (int kb = 0; kb < 2; ++kb) {
        int row = wm * 32 + mi * 16 + cl;
        int byte = row * 128 + kb * 64 + gq * 16;
        byte ^= ((row & 7) << 4);
        af[mi][kb] = *(const bf16x8*)((const char*)lA + byte);
      }
#pragma unroll
    for (int ni = 0; ni < 2; ++ni)
#pragma unroll
      for (int kb = 0; kb < 2; ++kb) {
        int row = wn * 32 + ni * 16 + cl;
        int byte = row * 128 + kb * 64 + gq * 16;
        byte ^= ((row & 7) << 4);
        bff[ni][kb] = *(const bf16x8*)((const char*)lB + byte);
      }
#pragma unroll
    for (int mi = 0; mi < 2; ++mi)
#pragma unroll
      for (int ni = 0; ni < 2; ++ni) {
        acc[mi][ni] = mfma16x16x32(af[mi][0], bff[ni][0], acc[mi][ni]);
        acc[mi][ni] = mfma16x16x32(af[mi][1], bff[ni][1], acc[mi][ni]);
      }
    __syncthreads();
  }

#pragma unroll
  for (int mi = 0; mi < 2; ++mi)
#pragma unroll
    for (int ni = 0; ni < 2; ++ni) {
      int n = bx + wn * 32 + ni * 16 + cl;
      float ub = 0.f, vb = 0.f;
      if (mode == 0) { ub = uvec[n]; vb = vvec[n]; }
#pragma unroll
      for (int r = 0; r < 4; ++r) {
        int m = by + wm * 32 + mi * 16 + 4 * gq + r;
        float val = acc[mi][ni][r];
        if (mode == 0) {
          // softmax scale (1/8) folded in here
          qu[(size_t)m * 1024 + n] = f2bf((val + ub) * 0.125f);
          qv[(size_t)m * 1024 + n] = f2bf((val + vb) * 0.125f);
        } else if (mode == 1) {
          dout[2097152 + (size_t)m * 1024 + n] = val;
          kbuf[(((size_t)((m >> 10) * 16 + (n >> 6))) * 2048 + 1024 + (m & 1023)) * 64 +
               (n & 63)] = f2bf(val);
        } else if (mode == 2) {
          dout[4194304 + (size_t)m * 1024 + n] = val;
          vtbuf[(((size_t)((m >> 10) * 16 + (n >> 6))) * 64 + (n & 63)) * 2048 + 1024 +
                (m & 1023)] = f2bf(val);
        } else if (mode == 3) {
          rbuf[((size_t)(n >> 6) * 2048 + m) * 64 + (n & 63)] = f2bf(val);
        } else {
          dout[(size_t)m * 1024 + n] = val;
        }
      }
    }
}

// --- flash attention, split-key, 1 wave / 16 q-rows per block ---------------
// grid x in [0,128) = chunk*64 + qt, y = h, z = b (XCD remap inside)
__global__ __launch_bounds__(64, 3) void attn_kernel(
    const u16* __restrict__ qu, const u16* __restrict__ qv,
    const u16* __restrict__ kbuf, const u16* __restrict__ vtbuf,
    const u16* __restrict__ rbuf, const int* __restrict__ qseg,
    const int* __restrict__ kseg, u16* __restrict__ pO,
    float* __restrict__ pml) {
  __shared__ __align__(16) u16 ldsP[16 * 64];  // 2KB, wave-private

  const int lane = threadIdx.x;
  const int gq = lane >> 4, cl = lane & 15;
  // XCD-locality remap (bijective over 4096): 4 (b,h) per XCD
  int lin = blockIdx.x + 128 * (blockIdx.y + 16 * blockIdx.z);
  lin = (lin & 7) * 512 + (lin >> 3);
  const int xx = lin & 127, bh = lin >> 7;
  const int chunk = xx >> 6, qt = xx & 63;
  const int b = bh >> 4, h = bh & 15;
  const int i0 = qt * 16;
  const int tmax = (i0 + 15 + 1024) >> 6;
  const f32x4 fz = {0.f, 0.f, 0.f, 0.f};

  const u16* Kb = kbuf + (size_t)bh * 2048 * 64;   // [s][d=64]
  const u16* Vb = vtbuf + (size_t)bh * 64 * 2048;  // [d][s=2048]
  const u16* rbh = rbuf + (size_t)h * 2048 * 64;   // [e][d=64]
  const int* ksegb = kseg + (size_t)b * 2048;

  // Q fragments (pre-scaled by 1/8): row=cl, k=32*kb+8*gq+j
  bf16x8 aU[2], aV[2];
#pragma unroll
  for (int kb = 0; kb < 2; ++kb) {
    size_t off = ((size_t)b * 1024 + i0 + cl) * 1024 + h * 64 + kb * 32 + gq * 8;
    aU[kb] = *(const bf16x8*)(qu + off);
    aV[kb] = *(const bf16x8*)(qv + off);
  }
  // loop-invariant per-row constants
  int qsv[4], srcl[4], athr[4];
  bool sel[4];
#pragma unroll
  for (int r = 0; r < 4; ++r) {
    int ri = 4 * gq + r;
    qsv[r] = qseg[b * 1024 + i0 + ri];
    int lc = cl - ri + 15;  // in [0,30]
    srcl[r] = (gq << 4) | (lc & 15);
    sel[r] = (lc < 16);
    athr[r] = i0 + ri + 1024 - cl;  // causal: j0t+16jt <= athr
  }

  float mrun[4], lrun[4];
  f32x4 oacc[4];
#pragma unroll
  for (int r = 0; r < 4; ++r) { mrun[r] = -1e30f; lrun[r] = 0.f; }
#pragma unroll
  for (int di = 0; di < 4; ++di) oacc[di] = fz;

  for (int t = chunk; t <= tmax; t += 2) {
    const int j0t = t * 64;
    const int Rb0 = j0t - i0 + 1008;  // 16-aligned band base, >= 0
    // ---- batch-issue ALL tile loads (independent; one latency exposure) ----
    bf16x8 Kf[4][2];
#pragma unroll
    for (int jt = 0; jt < 4; ++jt) {
      const u16* kp = Kb + (size_t)(j0t + 16 * jt + cl) * 64 + gq * 8;
      Kf[jt][0] = *(const bf16x8*)kp;
      Kf[jt][1] = *(const bf16x8*)(kp + 32);
    }
    bf16x8 Rf[5][2];
#pragma unroll
    for (int p = 0; p < 5; ++p) {
      const u16* rp = rbh + (size_t)min(Rb0 + 16 * p + cl, 2047) * 64 + gq * 8;
      Rf[p][0] = *(const bf16x8*)rp;
      Rf[p][1] = *(const bf16x8*)(rp + 32);
    }
    int ksv[4];
#pragma unroll
    for (int jt = 0; jt < 4; ++jt) ksv[jt] = ksegb[j0t + 16 * jt + cl];

    // ---- QK^T and bias-band MFMAs (bands shared: bd1[jt] == bd0[jt+1]) ----
    f32x4 xq[4];
#pragma unroll
    for (int jt = 0; jt < 4; ++jt) {
      f32x4 a = mfma16x16x32(aU[0], Kf[jt][0], fz);
      xq[jt] = mfma16x16x32(aU[1], Kf[jt][1], a);
    }
    f32x4 bb[5];
#pragma unroll
    for (int p = 0; p < 5; ++p) {
      f32x4 a = mfma16x16x32(aV[0], Rf[p][0], fz);
      bb[p] = mfma16x16x32(aV[1], Rf[p][1], a);
    }
    // ---- diagonal gather: 20 independent bpermutes ----
    float D[5][4];
#pragma unroll
    for (int p = 0; p < 5; ++p)
#pragma unroll
      for (int r = 0; r < 4; ++r) D[p][r] = __shfl(bb[p][r], srcl[r]);

    // ---- V preload for PV (latency hidden under softmax) ----
    bf16x8 Vf[4][2];
#pragma unroll
    for (int di = 0; di < 4; ++di) {
      const u16* vp = Vb + (size_t)(di * 16 + cl) * 2048 + j0t + gq * 8;
      Vf[di][0] = *(const bf16x8*)vp;
      Vf[di][1] = *(const bf16x8*)(vp + 32);
    }

    // ---- scores + mask ----
    float x[4][4];
#pragma unroll
    for (int jt = 0; jt < 4; ++jt)
#pragma unroll
      for (int r = 0; r < 4; ++r) {
        float bdv = sel[r] ? D[jt][r] : D[jt + 1][r];
        bool ok = (j0t + 16 * jt <= athr[r]) && (ksv[jt] == qsv[r]);
        x[jt][r] = ok ? (xq[jt][r] + bdv) : -1e30f;
      }

    // ---- online softmax (DPP allreduce, VALU pipe) ----
    char* Pm = (char*)ldsP;
    float alf[4];
#pragma unroll
    for (int r = 0; r < 4; ++r) {
      float mx = fmaxf(fmaxf(x[0][r], x[1][r]), fmaxf(x[2][r], x[3][r]));
      mx = dpp_max16(mx);
      float mold = mrun[r];
      float mnew = fmaxf(mold, mx);
      float al = __expf(mold - mnew);
      float p0 = __expf(x[0][r] - mnew);
      float p1 = __expf(x[1][r] - mnew);
      float p2 = __expf(x[2][r] - mnew);
      float p3 = __expf(x[3][r] - mnew);
      float s = dpp_sum16(p0 + p1 + p2 + p3);
      mrun[r] = mnew;
      lrun[r] = lrun[r] * al + s;
      alf[r] = al;
      int ri = 4 * gq + r;
      int bbx = (ri & 7) << 4;
      *(u16*)(Pm + ((ri * 128 + cl * 2) ^ bbx)) = f2bf(p0);
      *(u16*)(Pm + ((ri * 128 + (16 + cl) * 2) ^ bbx)) = f2bf(p1);
      *(u16*)(Pm + ((ri * 128 + (32 + cl) * 2) ^ bbx)) = f2bf(p2);
      *(u16*)(Pm + ((ri * 128 + (48 + cl) * 2) ^ bbx)) = f2bf(p3);
    }
    f32x4 av = {alf[0], alf[1], alf[2], alf[3]};
#pragma unroll
    for (int di = 0; di < 4; ++di) oacc[di] *= av;
    // ---- PV (P round-trip same-wave; V already in regs) ----
    int psw = (cl & 7) << 4;
    bf16x8 pf0 = *(const bf16x8*)(Pm + ((cl * 128 + gq * 16) ^ psw));
    bf16x8 pf1 = *(const bf16x8*)(Pm + ((cl * 128 + 64 + gq * 16) ^ psw));
#pragma unroll
    for (int di = 0; di < 4; ++di) {
      oacc[di] = mfma16x16x32(pf0, Vf[di][0], oacc[di]);
      oacc[di] = mfma16x16x32(pf1, Vf[di][1], oacc[di]);
    }
  }

  // epilogue: raw partials (no 1/l) + (m,l)
#pragma unroll
  for (int r = 0; r < 4; ++r) {
    int iq = i0 + 4 * gq + r;
    size_t rowp = ((size_t)bh * 2 + chunk) * 1024 + iq;
#pragma unroll
    for (int di = 0; di < 4; ++di)
      pO[rowp * 64 + di * 16 + cl] = f2bf(oacc[di][r]);
    if (cl == 0) {
      pml[rowp * 2] = mrun[r];
      pml[rowp * 2 + 1] = lrun[r];
    }
  }
}

// --- split-key combine -------------------------------------------------------
__global__ __launch_bounds__(256) void combine_kernel(
    const u16* __restrict__ pO, const float* __restrict__ pml,
    u16* __restrict__ obf) {
  int gid = blockIdx.x * 256 + threadIdx.x;  // 262144
  int d8 = (gid & 7) * 8;
  int row = gid >> 3;  // bh*1024 + iq
  int bh = row >> 10, iq = row & 1023;
  int b = bh >> 4, h = bh & 15;
  size_t r0 = ((size_t)bh * 2) * 1024 + iq;
  size_t r1 = r0 + 1024;
  float m0 = pml[r0 * 2], l0 = pml[r0 * 2 + 1];
  float m1 = pml[r1 * 2], l1 = pml[r1 * 2 + 1];
  float ms = fmaxf(m0, m1);
  float w0 = __expf(m0 - ms), w1 = __expf(m1 - ms);
  float inv = 1.0f / fmaxf(l0 * w0 + l1 * w1, 1e-30f);
  bf16x8 a = *(const bf16x8*)(pO + r0 * 64 + d8);
  bf16x8 c = *(const bf16x8*)(pO + r1 * 64 + d8);
  bf16x8 o;
#pragma unroll
  for (int j = 0; j < 8; ++j) {
    float f = (bf2f((u16)a[j]) * w0 + bf2f((u16)c[j]) * w1) * inv;
    o[j] = (short)f2bf(f);
  }
  *(bf16x8*)(obf + ((size_t)b * 1024 + iq) * 1024 + h * 64 + d8) = o;
}

// ---------------------------------------------------------------------------
extern "C" void kernel_launch(void* const* d_in, const int* in_sizes, int n_in,
                              void* d_out, int out_size, void* d_ws, size_t ws_size,
                              hipStream_t stream) {
  (void)in_sizes; (void)n_in; (void)out_size; (void)ws_size;
  const float* x           = (const float*)d_in[0];
  const int*   mask        = (const int*)d_in[1];
  const int*   mem_mask    = (const int*)d_in[3];
  const float* cache_key   = (const float*)d_in[4];
  const float* cache_value = (const float*)d_in[5];
  const int*   cache_mask  = (const int*)d_in[6];
  const float* rel_emb     = (const float*)d_in[7];
  const float* Wq          = (const float*)d_in[8];
  const float* Wk          = (const float*)d_in[9];
  const float* Wv          = (const float*)d_in[10];
  const float* Wr          = (const float*)d_in[11];
  const float* uvec        = (const float*)d_in[12];
  const float* vvec        = (const float*)d_in[13];
  const float* Wo          = (const float*)d_in[14];
  float* dout = (float*)d_out;

  char* W = (char*)d_ws;  // ~50.6 MB of workspace used
  u16* xbf   = (u16*)(W + (0u << 20));   // dead after projection GEMMs
  u16* relbf = (u16*)(W + (4u << 20));   // dead after projection GEMMs
  u16* pO    = (u16*)(W + (0u << 20));   // reuses xbf+relbf (8 MiB exactly)
  u16* wt5   = (u16*)(W + (8u << 20));
  u16* kbuf  = (u16*)(W + (18u << 20));
  u16* vtbuf = (u16*)(W + (26u << 20));
  u16* rbuf  = (u16*)(W + (34u << 20));
  u16* qu    = (u16*)(W + (38u << 20));
  u16* qv    = (u16*)(W + (42u << 20));
  u16* obf   = (u16*)(W + (46u << 20));
  int* qseg  = (int*)(W + (50u << 20));
  int* kseg  = (int*)(W + (50u << 20) + 8192);
  float* pml = (float*)(W + (50u << 20) + 32768);

  seg_scan_kernel<<<dim3(2), dim3(64), 0, stream>>>(mask, mem_mask, cache_mask, qseg, kseg);
  cvt_bf16_kernel<<<dim3(2048), dim3(256), 0, stream>>>(x, xbf, 2097152);
  cvt_bf16_kernel<<<dim3(2048), dim3(256), 0, stream>>>(rel_emb, relbf, 2097152);
  tr_w_kernel<<<dim3(32, 32), dim3(256), 0, stream>>>(Wq, wt5);
  tr_w_kernel<<<dim3(32, 32), dim3(256), 0, stream>>>(Wk, wt5 + (1u << 20));
  tr_w_kernel<<<dim3(32, 32), dim3(256), 0, stream>>>(Wv, wt5 + (2u << 20));
  tr_w_kernel<<<dim3(32, 32), dim3(256), 0, stream>>>(Wr, wt5 + (3u << 20));
  tr_w_kernel<<<dim3(32, 32), dim3(256), 0, stream>>>(Wo, wt5 + (4u << 20));
  ck_perm_kernel<<<dim3(2048), dim3(256), 0, stream>>>(cache_key, kbuf);
  cv_tr_kernel<<<dim3(32, 2, 32), dim3(256), 0, stream>>>(cache_value, vtbuf);
  gemm_proj_kernel<<<dim3(16, 32, 4), dim3(256), 0, stream>>>(
      xbf, relbf, obf, wt5, qu, qv, kbuf, vtbuf, rbuf, dout, uvec, vvec, -1);
  attn_kernel<<<dim3(128, 16, 2), dim3(64), 0, stream>>>(qu, qv, kbuf, vtbuf, rbuf,
                                                         qseg, kseg, pO, pml);
  combine_kernel<<<dim3(1024), dim3(256), 0, stream>>>(pO, pml, obf);
  gemm_proj_kernel<<<dim3(16, 32, 1), dim3(256), 0, stream>>>(
      xbf, relbf, obf, wt5, qu, qv, kbuf, vtbuf, rbuf, dout, uvec, vvec, 4);
}

// Round 6
// 285.978 us; speedup vs baseline: 1.5471x; 1.0068x over previous
//
#include <hip/hip_runtime.h>
#include <climits>

// ---------------------------------------------------------------------------
// RelativeMultiHeadAttentionBlock (Transformer-XL style) on MI355X (gfx950)
// B=2, T=C=1024, M=1024, S=2048, H=16, HD=64, F=1024. fp32 in/out, bf16 MFMA.
//
// R5: the R4 post-mortem showed VGPR=68 -> the ~30 tile loads were register-
// starved and fully serialized (~17k stall cy/tile). One change:
//   __launch_bounds__(64, 2) (VGPR cap 256) + V loads hoisted into the top
//   batch, so one wave keeps ~30 L2 loads in flight (ILP replaces the TLP we
//   never actually had). Shape unchanged: 4096 one-wave blocks, 2-way split,
//   XCD remap (L2-resident, FETCH ~16MB), DPP softmax, band-shared bias.
// ---------------------------------------------------------------------------

typedef unsigned short u16;
typedef short bf16x8 __attribute__((ext_vector_type(8)));
typedef float f32x4 __attribute__((ext_vector_type(4)));

__device__ __forceinline__ f32x4 mfma16x16x32(bf16x8 a, bf16x8 b, f32x4 c) {
  return __builtin_amdgcn_mfma_f32_16x16x32_bf16(a, b, c, 0, 0, 0);
}

__device__ __forceinline__ u16 f2bf(float f) {  // RNE f32->bf16
  unsigned u = __builtin_bit_cast(unsigned, f);
  u = (u + 0x7FFFu + ((u >> 16) & 1u)) >> 16;
  return (u16)u;
}

__device__ __forceinline__ float bf2f(u16 x) {
  unsigned u = ((unsigned)x) << 16;
  return __builtin_bit_cast(float, u);
}

__device__ __forceinline__ void gll16(const void* g, void* l) {
  __builtin_amdgcn_global_load_lds(
      (const __attribute__((address_space(1))) void*)g,
      (__attribute__((address_space(3))) void*)l, 16, 0, 0);
}

// DPP 16-lane rotation allreduce (VALU pipe; rows of 16 = our gq groups)
template <int CTRL>
__device__ __forceinline__ float rot16(float x) {
  int i = __builtin_bit_cast(int, x);
  int r = __builtin_amdgcn_update_dpp(i, i, CTRL, 0xF, 0xF, false);
  return __builtin_bit_cast(float, r);
}
__device__ __forceinline__ float dpp_max16(float x) {
  x = fmaxf(x, rot16<0x128>(x));  // ror:8
  x = fmaxf(x, rot16<0x124>(x));  // ror:4
  x = fmaxf(x, rot16<0x122>(x));  // ror:2
  x = fmaxf(x, rot16<0x121>(x));  // ror:1
  return x;
}
__device__ __forceinline__ float dpp_sum16(float x) {
  x += rot16<0x128>(x);
  x += rot16<0x124>(x);
  x += rot16<0x122>(x);
  x += rot16<0x121>(x);
  return x;
}

// --- segment ids ------------------------------------------------------------
__global__ __launch_bounds__(64) void seg_scan_kernel(
    const int* __restrict__ mask, const int* __restrict__ mem_mask,
    const int* __restrict__ cache_mask, int* __restrict__ qseg,
    int* __restrict__ kseg) {
  __shared__ int cs[3072];
  int b = blockIdx.x, lane = threadIdx.x;
  int carry = 0;
  for (int base = 0; base < 3072; base += 64) {
    int idx = base + lane;
    int val;
    if (idx < 1024)      val = mem_mask[b * 1024 + idx];
    else if (idx < 2048) val = cache_mask[b * 1024 + idx - 1024];
    else                 val = mask[b * 1024 + idx - 2048];
    for (int o = 1; o < 64; o <<= 1) {
      int n = __shfl_up(val, o);
      if (lane >= o) val += n;
    }
    val += carry;
    cs[idx] = val;
    carry = __shfl(val, 63);
  }
  __syncthreads();
  int mx = INT_MIN;
  for (int i = lane; i < 2048; i += 64) mx = max(mx, cs[i]);
  for (int o = 1; o < 64; o <<= 1) mx = max(mx, __shfl_xor(mx, o));
  int cs2047 = cs[2047];
  for (int t = lane; t < 1024; t += 64) qseg[b * 1024 + t] = cs[2048 + t] - cs2047 + mx;
  for (int j = lane; j < 2048; j += 64) kseg[b * 2048 + j] = cs[1024 + j];
}

// --- preps ------------------------------------------------------------------
__global__ __launch_bounds__(256) void cvt_bf16_kernel(const float* __restrict__ src,
                                                       u16* __restrict__ dst, int n) {
  int i = (blockIdx.x * 256 + threadIdx.x) * 4;
  if (i >= n) return;
  float4 v = *(const float4*)(src + i);
  dst[i + 0] = f2bf(v.x); dst[i + 1] = f2bf(v.y);
  dst[i + 2] = f2bf(v.z); dst[i + 3] = f2bf(v.w);
}

__global__ __launch_bounds__(256) void tr_w_kernel(const float* __restrict__ src,
                                                   u16* __restrict__ dst) {
  __shared__ float tile[32][33];
  int tx = threadIdx.x & 31, ty = threadIdx.x >> 5;
  int r0 = blockIdx.y * 32, c0 = blockIdx.x * 32;
#pragma unroll
  for (int i = 0; i < 32; i += 8)
    tile[ty + i][tx] = src[(size_t)(r0 + ty + i) * 1024 + c0 + tx];
  __syncthreads();
#pragma unroll
  for (int i = 0; i < 32; i += 8)
    dst[(size_t)(c0 + ty + i) * 1024 + r0 + tx] = f2bf(tile[tx][ty + i]);
}

__global__ __launch_bounds__(256) void ck_perm_kernel(const float* __restrict__ src,
                                                      u16* __restrict__ dst) {
  int i = blockIdx.x * 256 + threadIdx.x;  // 524288 quads
  int dq = i & 15, h = (i >> 4) & 15, t = (i >> 8) & 1023, b = i >> 18;
  float4 v = *(const float4*)(src + (size_t)i * 4);
  size_t o = (((size_t)(b * 16 + h)) * 2048 + t) * 64 + dq * 4;
  dst[o + 0] = f2bf(v.x); dst[o + 1] = f2bf(v.y);
  dst[o + 2] = f2bf(v.z); dst[o + 3] = f2bf(v.w);
}

__global__ __launch_bounds__(256) void cv_tr_kernel(const float* __restrict__ src,
                                                    u16* __restrict__ dst) {
  __shared__ float tile[32][33];
  int bh = blockIdx.z, b = bh >> 4, h = bh & 15;
  int t0 = blockIdx.x * 32, d0 = blockIdx.y * 32;
  int tx = threadIdx.x & 31, ty = threadIdx.x >> 5;
#pragma unroll
  for (int i = 0; i < 32; i += 8)
    tile[ty + i][tx] = src[(((size_t)b * 1024 + t0 + ty + i) * 16 + h) * 64 + d0 + tx];
  __syncthreads();
#pragma unroll
  for (int i = 0; i < 32; i += 8)
    dst[((size_t)bh * 64 + d0 + ty + i) * 2048 + t0 + tx] = f2bf(tile[tx][ty + i]);
}

// --- projection / output GEMM ----------------------------------------------
__global__ __launch_bounds__(256) void gemm_proj_kernel(
    const u16* __restrict__ xbf, const u16* __restrict__ relbf,
    const u16* __restrict__ obf, const u16* __restrict__ wt5,
    u16* __restrict__ qu, u16* __restrict__ qv, u16* __restrict__ kbuf,
    u16* __restrict__ vtbuf, u16* __restrict__ rbuf, float* __restrict__ dout,
    const float* __restrict__ uvec, const float* __restrict__ vvec, int movr) {
  __shared__ __align__(16) u16 lA[64 * 64];
  __shared__ __align__(16) u16 lB[64 * 64];
  const int mode = (movr >= 0) ? movr : (int)blockIdx.z;
  const u16* A = (mode == 3) ? relbf : ((mode == 4) ? obf : xbf);
  const u16* Wm = wt5 + (size_t)mode * 1048576;
  const int tid = threadIdx.x;
  const int lane = tid & 63, gq = lane >> 4, cl = lane & 15;
  const int wv = tid >> 6, wm = wv >> 1, wn = wv & 1;
  const int by = blockIdx.y * 64, bx = blockIdx.x * 64;
  const f32x4 fz = {0.f, 0.f, 0.f, 0.f};

  f32x4 acc[2][2];
#pragma unroll
  for (int a = 0; a < 2; ++a)
#pragma unroll
    for (int bq = 0; bq < 2; ++bq) acc[a][bq] = fz;

  const int off0 = tid * 16, off1 = tid * 16 + 4096;
  const int L0 = off0 ^ (((off0 >> 7) & 7) << 4);
  const int L1 = off1 ^ (((off1 >> 7) & 7) << 4);
  const int rr0 = off0 >> 7, ke0 = (L0 & 127) >> 1;
  const int rr1 = off1 >> 7, ke1 = (L1 & 127) >> 1;
  const u16* pA0 = A + (size_t)(by + rr0) * 1024 + ke0;
  const u16* pA1 = A + (size_t)(by + rr1) * 1024 + ke1;
  const u16* pB0 = Wm + (size_t)(bx + rr0) * 1024 + ke0;
  const u16* pB1 = Wm + (size_t)(bx + rr1) * 1024 + ke1;

  for (int k0 = 0; k0 < 1024; k0 += 64) {
    gll16(pA0 + k0, (char*)lA + off0);
    gll16(pA1 + k0, (char*)lA + off1);
    gll16(pB0 + k0, (char*)lB + off0);
    gll16(pB1 + k0, (char*)lB + off1);
    __syncthreads();
    bf16x8 af[2][2], bff[2][2];
#pragma unroll
    for (int mi = 0; mi < 2; ++mi)
#pragma unroll
      for (int kb = 0; kb < 2; ++kb) {
        int row = wm * 32 + mi * 16 + cl;
        int byte = row * 128 + kb * 64 + gq * 16;
        byte ^= ((row & 7) << 4);
        af[mi][kb] = *(const bf16x8*)((const char*)lA + byte);
      }
#pragma unroll
    for (int ni = 0; ni < 2; ++ni)
#pragma unroll
      for (int kb = 0; kb < 2; ++kb) {
        int row = wn * 32 + ni * 16 + cl;
        int byte = row * 128 + kb * 64 + gq * 16;
        byte ^= ((row & 7) << 4);
        bff[ni][kb] = *(const bf16x8*)((const char*)lB + byte);
      }
#pragma unroll
    for (int mi = 0; mi < 2; ++mi)
#pragma unroll
      for (int ni = 0; ni < 2; ++ni) {
        acc[mi][ni] = mfma16x16x32(af[mi][0], bff[ni][0], acc[mi][ni]);
        acc[mi][ni] = mfma16x16x32(af[mi][1], bff[ni][1], acc[mi][ni]);
      }
    __syncthreads();
  }

#pragma unroll
  for (int mi = 0; mi < 2; ++mi)
#pragma unroll
    for (int ni = 0; ni < 2; ++ni) {
      int n = bx + wn * 32 + ni * 16 + cl;
      float ub = 0.f, vb = 0.f;
      if (mode == 0) { ub = uvec[n]; vb = vvec[n]; }
#pragma unroll
      for (int r = 0; r < 4; ++r) {
        int m = by + wm * 32 + mi * 16 + 4 * gq + r;
        float val = acc[mi][ni][r];
        if (mode == 0) {
          // softmax scale (1/8) folded in here
          qu[(size_t)m * 1024 + n] = f2bf((val + ub) * 0.125f);
          qv[(size_t)m * 1024 + n] = f2bf((val + vb) * 0.125f);
        } else if (mode == 1) {
          dout[2097152 + (size_t)m * 1024 + n] = val;
          kbuf[(((size_t)((m >> 10) * 16 + (n >> 6))) * 2048 + 1024 + (m & 1023)) * 64 +
               (n & 63)] = f2bf(val);
        } else if (mode == 2) {
          dout[4194304 + (size_t)m * 1024 + n] = val;
          vtbuf[(((size_t)((m >> 10) * 16 + (n >> 6))) * 64 + (n & 63)) * 2048 + 1024 +
                (m & 1023)] = f2bf(val);
        } else if (mode == 3) {
          rbuf[((size_t)(n >> 6) * 2048 + m) * 64 + (n & 63)] = f2bf(val);
        } else {
          dout[(size_t)m * 1024 + n] = val;
        }
      }
    }
}

// --- flash attention, split-key, 1 wave / 16 q-rows per block ---------------
// grid x in [0,128) = chunk*64 + qt, y = h, z = b (XCD remap inside)
// launch_bounds(64,2): VGPR cap 256 so the whole tile's ~30 loads stay in
// flight together (R4 post-mortem: at 68 VGPR they serialize at ~500cy each).
__global__ __launch_bounds__(64, 2) void attn_kernel(
    const u16* __restrict__ qu, const u16* __restrict__ qv,
    const u16* __restrict__ kbuf, const u16* __restrict__ vtbuf,
    const u16* __restrict__ rbuf, const int* __restrict__ qseg,
    const int* __restrict__ kseg, u16* __restrict__ pO,
    float* __restrict__ pml) {
  __shared__ __align__(16) u16 ldsP[16 * 64];  // 2KB, wave-private

  const int lane = threadIdx.x;
  const int gq = lane >> 4, cl = lane & 15;
  // XCD-locality remap (bijective over 4096): 4 (b,h) per XCD
  int lin = blockIdx.x + 128 * (blockIdx.y + 16 * blockIdx.z);
  lin = (lin & 7) * 512 + (lin >> 3);
  const int xx = lin & 127, bh = lin >> 7;
  const int chunk = xx >> 6, qt = xx & 63;
  const int b = bh >> 4, h = bh & 15;
  const int i0 = qt * 16;
  const int tmax = (i0 + 15 + 1024) >> 6;
  const f32x4 fz = {0.f, 0.f, 0.f, 0.f};

  const u16* Kb = kbuf + (size_t)bh * 2048 * 64;   // [s][d=64]
  const u16* Vb = vtbuf + (size_t)bh * 64 * 2048;  // [d][s=2048]
  const u16* rbh = rbuf + (size_t)h * 2048 * 64;   // [e][d=64]
  const int* ksegb = kseg + (size_t)b * 2048;

  // Q fragments (pre-scaled by 1/8): row=cl, k=32*kb+8*gq+j
  bf16x8 aU[2], aV[2];
#pragma unroll
  for (int kb = 0; kb < 2; ++kb) {
    size_t off = ((size_t)b * 1024 + i0 + cl) * 1024 + h * 64 + kb * 32 + gq * 8;
    aU[kb] = *(const bf16x8*)(qu + off);
    aV[kb] = *(const bf16x8*)(qv + off);
  }
  // loop-invariant per-row constants
  int qsv[4], srcl[4], athr[4];
  bool sel[4];
#pragma unroll
  for (int r = 0; r < 4; ++r) {
    int ri = 4 * gq + r;
    qsv[r] = qseg[b * 1024 + i0 + ri];
    int lc = cl - ri + 15;  // in [0,30]
    srcl[r] = (gq << 4) | (lc & 15);
    sel[r] = (lc < 16);
    athr[r] = i0 + ri + 1024 - cl;  // causal: j0t+16jt <= athr
  }

  float mrun[4], lrun[4];
  f32x4 oacc[4];
#pragma unroll
  for (int r = 0; r < 4; ++r) { mrun[r] = -1e30f; lrun[r] = 0.f; }
#pragma unroll
  for (int di = 0; di < 4; ++di) oacc[di] = fz;

  for (int t = chunk; t <= tmax; t += 2) {
    const int j0t = t * 64;
    const int Rb0 = j0t - i0 + 1008;  // 16-aligned band base, >= 0
    // ---- batch-issue ALL tile loads (K, R, V, kseg) up front: with the
    // (64,2) register budget these ~30 loads stay in flight together ----
    bf16x8 Kf[4][2];
#pragma unroll
    for (int jt = 0; jt < 4; ++jt) {
      const u16* kp = Kb + (size_t)(j0t + 16 * jt + cl) * 64 + gq * 8;
      Kf[jt][0] = *(const bf16x8*)kp;
      Kf[jt][1] = *(const bf16x8*)(kp + 32);
    }
    bf16x8 Rf[5][2];
#pragma unroll
    for (int p = 0; p < 5; ++p) {
      const u16* rp = rbh + (size_t)min(Rb0 + 16 * p + cl, 2047) * 64 + gq * 8;
      Rf[p][0] = *(const bf16x8*)rp;
      Rf[p][1] = *(const bf16x8*)(rp + 32);
    }
    bf16x8 Vf[4][2];
#pragma unroll
    for (int di = 0; di < 4; ++di) {
      const u16* vp = Vb + (size_t)(di * 16 + cl) * 2048 + j0t + gq * 8;
      Vf[di][0] = *(const bf16x8*)vp;
      Vf[di][1] = *(const bf16x8*)(vp + 32);
    }
    int ksv[4];
#pragma unroll
    for (int jt = 0; jt < 4; ++jt) ksv[jt] = ksegb[j0t + 16 * jt + cl];

    // ---- QK^T and bias-band MFMAs (bands shared: bd1[jt] == bd0[jt+1]) ----
    f32x4 xq[4];
#pragma unroll
    for (int jt = 0; jt < 4; ++jt) {
      f32x4 a = mfma16x16x32(aU[0], Kf[jt][0], fz);
      xq[jt] = mfma16x16x32(aU[1], Kf[jt][1], a);
    }
    f32x4 bb[5];
#pragma unroll
    for (int p = 0; p < 5; ++p) {
      f32x4 a = mfma16x16x32(aV[0], Rf[p][0], fz);
      bb[p] = mfma16x16x32(aV[1], Rf[p][1], a);
    }
    // ---- diagonal gather: 20 independent bpermutes ----
    float D[5][4];
#pragma unroll
    for (int p = 0; p < 5; ++p)
#pragma unroll
      for (int r = 0; r < 4; ++r) D[p][r] = __shfl(bb[p][r], srcl[r]);

    // ---- scores + mask ----
    float x[4][4];
#pragma unroll
    for (int jt = 0; jt < 4; ++jt)
#pragma unroll
      for (int r = 0; r < 4; ++r) {
        float bdv = sel[r] ? D[jt][r] : D[jt + 1][r];
        bool ok = (j0t + 16 * jt <= athr[r]) && (ksv[jt] == qsv[r]);
        x[jt][r] = ok ? (xq[jt][r] + bdv) : -1e30f;
      }

    // ---- online softmax (DPP allreduce, VALU pipe) ----
    char* Pm = (char*)ldsP;
    float alf[4];
#pragma unroll
    for (int r = 0; r < 4; ++r) {
      float mx = fmaxf(fmaxf(x[0][r], x[1][r]), fmaxf(x[2][r], x[3][r]));
      mx = dpp_max16(mx);
      float mold = mrun[r];
      float mnew = fmaxf(mold, mx);
      float al = __expf(mold - mnew);
      float p0 = __expf(x[0][r] - mnew);
      float p1 = __expf(x[1][r] - mnew);
      float p2 = __expf(x[2][r] - mnew);
      float p3 = __expf(x[3][r] - mnew);
      float s = dpp_sum16(p0 + p1 + p2 + p3);
      mrun[r] = mnew;
      lrun[r] = lrun[r] * al + s;
      alf[r] = al;
      int ri = 4 * gq + r;
      int bbx = (ri & 7) << 4;
      *(u16*)(Pm + ((ri * 128 + cl * 2) ^ bbx)) = f2bf(p0);
      *(u16*)(Pm + ((ri * 128 + (16 + cl) * 2) ^ bbx)) = f2bf(p1);
      *(u16*)(Pm + ((ri * 128 + (32 + cl) * 2) ^ bbx)) = f2bf(p2);
      *(u16*)(Pm + ((ri * 128 + (48 + cl) * 2) ^ bbx)) = f2bf(p3);
    }
    f32x4 av = {alf[0], alf[1], alf[2], alf[3]};
#pragma unroll
    for (int di = 0; di < 4; ++di) oacc[di] *= av;
    // ---- PV (P round-trip same-wave; V already in regs) ----
    int psw = (cl & 7) << 4;
    bf16x8 pf0 = *(const bf16x8*)(Pm + ((cl * 128 + gq * 16) ^ psw));
    bf16x8 pf1 = *(const bf16x8*)(Pm + ((cl * 128 + 64 + gq * 16) ^ psw));
#pragma unroll
    for (int di = 0; di < 4; ++di) {
      oacc[di] = mfma16x16x32(pf0, Vf[di][0], oacc[di]);
      oacc[di] = mfma16x16x32(pf1, Vf[di][1], oacc[di]);
    }
  }

  // epilogue: raw partials (no 1/l) + (m,l)
#pragma unroll
  for (int r = 0; r < 4; ++r) {
    int iq = i0 + 4 * gq + r;
    size_t rowp = ((size_t)bh * 2 + chunk) * 1024 + iq;
#pragma unroll
    for (int di = 0; di < 4; ++di)
      pO[rowp * 64 + di * 16 + cl] = f2bf(oacc[di][r]);
    if (cl == 0) {
      pml[rowp * 2] = mrun[r];
      pml[rowp * 2 + 1] = lrun[r];
    }
  }
}

// --- split-key combine -------------------------------------------------------
__global__ __launch_bounds__(256) void combine_kernel(
    const u16* __restrict__ pO, const float* __restrict__ pml,
    u16* __restrict__ obf) {
  int gid = blockIdx.x * 256 + threadIdx.x;  // 262144
  int d8 = (gid & 7) * 8;
  int row = gid >> 3;  // bh*1024 + iq
  int bh = row >> 10, iq = row & 1023;
  int b = bh >> 4, h = bh & 15;
  size_t r0 = ((size_t)bh * 2) * 1024 + iq;
  size_t r1 = r0 + 1024;
  float m0 = pml[r0 * 2], l0 = pml[r0 * 2 + 1];
  float m1 = pml[r1 * 2], l1 = pml[r1 * 2 + 1];
  float ms = fmaxf(m0, m1);
  float w0 = __expf(m0 - ms), w1 = __expf(m1 - ms);
  float inv = 1.0f / fmaxf(l0 * w0 + l1 * w1, 1e-30f);
  bf16x8 a = *(const bf16x8*)(pO + r0 * 64 + d8);
  bf16x8 c = *(const bf16x8*)(pO + r1 * 64 + d8);
  bf16x8 o;
#pragma unroll
  for (int j = 0; j < 8; ++j) {
    float f = (bf2f((u16)a[j]) * w0 + bf2f((u16)c[j]) * w1) * inv;
    o[j] = (short)f2bf(f);
  }
  *(bf16x8*)(obf + ((size_t)b * 1024 + iq) * 1024 + h * 64 + d8) = o;
}

// ---------------------------------------------------------------------------
extern "C" void kernel_launch(void* const* d_in, const int* in_sizes, int n_in,
                              void* d_out, int out_size, void* d_ws, size_t ws_size,
                              hipStream_t stream) {
  (void)in_sizes; (void)n_in; (void)out_size; (void)ws_size;
  const float* x           = (const float*)d_in[0];
  const int*   mask        = (const int*)d_in[1];
  const int*   mem_mask    = (const int*)d_in[3];
  const float* cache_key   = (const float*)d_in[4];
  const float* cache_value = (const float*)d_in[5];
  const int*   cache_mask  = (const int*)d_in[6];
  const float* rel_emb     = (const float*)d_in[7];
  const float* Wq          = (const float*)d_in[8];
  const float* Wk          = (const float*)d_in[9];
  const float* Wv          = (const float*)d_in[10];
  const float* Wr          = (const float*)d_in[11];
  const float* uvec        = (const float*)d_in[12];
  const float* vvec        = (const float*)d_in[13];
  const float* Wo          = (const float*)d_in[14];
  float* dout = (float*)d_out;

  char* W = (char*)d_ws;  // ~50.6 MB of workspace used
  u16* xbf   = (u16*)(W + (0u << 20));   // dead after projection GEMMs
  u16* relbf = (u16*)(W + (4u << 20));   // dead after projection GEMMs
  u16* pO    = (u16*)(W + (0u << 20));   // reuses xbf+relbf (8 MiB exactly)
  u16* wt5   = (u16*)(W + (8u << 20));
  u16* kbuf  = (u16*)(W + (18u << 20));
  u16* vtbuf = (u16*)(W + (26u << 20));
  u16* rbuf  = (u16*)(W + (34u << 20));
  u16* qu    = (u16*)(W + (38u << 20));
  u16* qv    = (u16*)(W + (42u << 20));
  u16* obf   = (u16*)(W + (46u << 20));
  int* qseg  = (int*)(W + (50u << 20));
  int* kseg  = (int*)(W + (50u << 20) + 8192);
  float* pml = (float*)(W + (50u << 20) + 32768);

  seg_scan_kernel<<<dim3(2), dim3(64), 0, stream>>>(mask, mem_mask, cache_mask, qseg, kseg);
  cvt_bf16_kernel<<<dim3(2048), dim3(256), 0, stream>>>(x, xbf, 2097152);
  cvt_bf16_kernel<<<dim3(2048), dim3(256), 0, stream>>>(rel_emb, relbf, 2097152);
  tr_w_kernel<<<dim3(32, 32), dim3(256), 0, stream>>>(Wq, wt5);
  tr_w_kernel<<<dim3(32, 32), dim3(256), 0, stream>>>(Wk, wt5 + (1u << 20));
  tr_w_kernel<<<dim3(32, 32), dim3(256), 0, stream>>>(Wv, wt5 + (2u << 20));
  tr_w_kernel<<<dim3(32, 32), dim3(256), 0, stream>>>(Wr, wt5 + (3u << 20));
  tr_w_kernel<<<dim3(32, 32), dim3(256), 0, stream>>>(Wo, wt5 + (4u << 20));
  ck_perm_kernel<<<dim3(2048), dim3(256), 0, stream>>>(cache_key, kbuf);
  cv_tr_kernel<<<dim3(32, 2, 32), dim3(256), 0, stream>>>(cache_value, vtbuf);
  gemm_proj_kernel<<<dim3(16, 32, 4), dim3(256), 0, stream>>>(
      xbf, relbf, obf, wt5, qu, qv, kbuf, vtbuf, rbuf, dout, uvec, vvec, -1);
  attn_kernel<<<dim3(128, 16, 2), dim3(64), 0, stream>>>(qu, qv, kbuf, vtbuf, rbuf,
                                                         qseg, kseg, pO, pml);
  combine_kernel<<<dim3(1024), dim3(256), 0, stream>>>(pO, pml, obf);
  gemm_proj_kernel<<<dim3(16, 32, 1), dim3(256), 0, stream>>>(
      xbf, relbf, obf, wt5, qu, qv, kbuf, vtbuf, rbuf, dout, uvec, vvec, 4);
}

// Round 7
// 270.976 us; speedup vs baseline: 1.6328x; 1.0554x over previous
//
#include <hip/hip_runtime.h>
#include <climits>

// ---------------------------------------------------------------------------
// RelativeMultiHeadAttentionBlock (Transformer-XL style) on MI355X (gfx950)
// B=2, T=C=1024, M=1024, S=2048, H=16, HD=64, F=1024. fp32 in/out, bf16 MFMA.
//
// R6: R5's VGPR=68 proved the scheduler sank each load next to its use
// (launch_bounds only caps; it doesn't force batching). Fix: sched_barrier(0)
// fences after (a) the 26-load tile batch and (b) the 20 bpermute gathers.
// Live-across-fence values force the RA to keep all loads in flight ->
// one L2 round-trip per tile instead of ~26 serial ones.
// Shape unchanged: 4096 one-wave blocks, 2-way split, XCD remap (FETCH
// ~16MB L2-resident), DPP softmax, band-shared bias.
// ---------------------------------------------------------------------------

typedef unsigned short u16;
typedef short bf16x8 __attribute__((ext_vector_type(8)));
typedef float f32x4 __attribute__((ext_vector_type(4)));

__device__ __forceinline__ f32x4 mfma16x16x32(bf16x8 a, bf16x8 b, f32x4 c) {
  return __builtin_amdgcn_mfma_f32_16x16x32_bf16(a, b, c, 0, 0, 0);
}

__device__ __forceinline__ u16 f2bf(float f) {  // RNE f32->bf16
  unsigned u = __builtin_bit_cast(unsigned, f);
  u = (u + 0x7FFFu + ((u >> 16) & 1u)) >> 16;
  return (u16)u;
}

__device__ __forceinline__ float bf2f(u16 x) {
  unsigned u = ((unsigned)x) << 16;
  return __builtin_bit_cast(float, u);
}

__device__ __forceinline__ void gll16(const void* g, void* l) {
  __builtin_amdgcn_global_load_lds(
      (const __attribute__((address_space(1))) void*)g,
      (__attribute__((address_space(3))) void*)l, 16, 0, 0);
}

// DPP 16-lane rotation allreduce (VALU pipe; rows of 16 = our gq groups)
template <int CTRL>
__device__ __forceinline__ float rot16(float x) {
  int i = __builtin_bit_cast(int, x);
  int r = __builtin_amdgcn_update_dpp(i, i, CTRL, 0xF, 0xF, false);
  return __builtin_bit_cast(float, r);
}
__device__ __forceinline__ float dpp_max16(float x) {
  x = fmaxf(x, rot16<0x128>(x));  // ror:8
  x = fmaxf(x, rot16<0x124>(x));  // ror:4
  x = fmaxf(x, rot16<0x122>(x));  // ror:2
  x = fmaxf(x, rot16<0x121>(x));  // ror:1
  return x;
}
__device__ __forceinline__ float dpp_sum16(float x) {
  x += rot16<0x128>(x);
  x += rot16<0x124>(x);
  x += rot16<0x122>(x);
  x += rot16<0x121>(x);
  return x;
}

// --- segment ids ------------------------------------------------------------
__global__ __launch_bounds__(64) void seg_scan_kernel(
    const int* __restrict__ mask, const int* __restrict__ mem_mask,
    const int* __restrict__ cache_mask, int* __restrict__ qseg,
    int* __restrict__ kseg) {
  __shared__ int cs[3072];
  int b = blockIdx.x, lane = threadIdx.x;
  int carry = 0;
  for (int base = 0; base < 3072; base += 64) {
    int idx = base + lane;
    int val;
    if (idx < 1024)      val = mem_mask[b * 1024 + idx];
    else if (idx < 2048) val = cache_mask[b * 1024 + idx - 1024];
    else                 val = mask[b * 1024 + idx - 2048];
    for (int o = 1; o < 64; o <<= 1) {
      int n = __shfl_up(val, o);
      if (lane >= o) val += n;
    }
    val += carry;
    cs[idx] = val;
    carry = __shfl(val, 63);
  }
  __syncthreads();
  int mx = INT_MIN;
  for (int i = lane; i < 2048; i += 64) mx = max(mx, cs[i]);
  for (int o = 1; o < 64; o <<= 1) mx = max(mx, __shfl_xor(mx, o));
  int cs2047 = cs[2047];
  for (int t = lane; t < 1024; t += 64) qseg[b * 1024 + t] = cs[2048 + t] - cs2047 + mx;
  for (int j = lane; j < 2048; j += 64) kseg[b * 2048 + j] = cs[1024 + j];
}

// --- preps ------------------------------------------------------------------
__global__ __launch_bounds__(256) void cvt_bf16_kernel(const float* __restrict__ src,
                                                       u16* __restrict__ dst, int n) {
  int i = (blockIdx.x * 256 + threadIdx.x) * 4;
  if (i >= n) return;
  float4 v = *(const float4*)(src + i);
  dst[i + 0] = f2bf(v.x); dst[i + 1] = f2bf(v.y);
  dst[i + 2] = f2bf(v.z); dst[i + 3] = f2bf(v.w);
}

__global__ __launch_bounds__(256) void tr_w_kernel(const float* __restrict__ src,
                                                   u16* __restrict__ dst) {
  __shared__ float tile[32][33];
  int tx = threadIdx.x & 31, ty = threadIdx.x >> 5;
  int r0 = blockIdx.y * 32, c0 = blockIdx.x * 32;
#pragma unroll
  for (int i = 0; i < 32; i += 8)
    tile[ty + i][tx] = src[(size_t)(r0 + ty + i) * 1024 + c0 + tx];
  __syncthreads();
#pragma unroll
  for (int i = 0; i < 32; i += 8)
    dst[(size_t)(c0 + ty + i) * 1024 + r0 + tx] = f2bf(tile[tx][ty + i]);
}

__global__ __launch_bounds__(256) void ck_perm_kernel(const float* __restrict__ src,
                                                      u16* __restrict__ dst) {
  int i = blockIdx.x * 256 + threadIdx.x;  // 524288 quads
  int dq = i & 15, h = (i >> 4) & 15, t = (i >> 8) & 1023, b = i >> 18;
  float4 v = *(const float4*)(src + (size_t)i * 4);
  size_t o = (((size_t)(b * 16 + h)) * 2048 + t) * 64 + dq * 4;
  dst[o + 0] = f2bf(v.x); dst[o + 1] = f2bf(v.y);
  dst[o + 2] = f2bf(v.z); dst[o + 3] = f2bf(v.w);
}

__global__ __launch_bounds__(256) void cv_tr_kernel(const float* __restrict__ src,
                                                    u16* __restrict__ dst) {
  __shared__ float tile[32][33];
  int bh = blockIdx.z, b = bh >> 4, h = bh & 15;
  int t0 = blockIdx.x * 32, d0 = blockIdx.y * 32;
  int tx = threadIdx.x & 31, ty = threadIdx.x >> 5;
#pragma unroll
  for (int i = 0; i < 32; i += 8)
    tile[ty + i][tx] = src[(((size_t)b * 1024 + t0 + ty + i) * 16 + h) * 64 + d0 + tx];
  __syncthreads();
#pragma unroll
  for (int i = 0; i < 32; i += 8)
    dst[((size_t)bh * 64 + d0 + ty + i) * 2048 + t0 + tx] = f2bf(tile[tx][ty + i]);
}

// --- projection / output GEMM ----------------------------------------------
__global__ __launch_bounds__(256) void gemm_proj_kernel(
    const u16* __restrict__ xbf, const u16* __restrict__ relbf,
    const u16* __restrict__ obf, const u16* __restrict__ wt5,
    u16* __restrict__ qu, u16* __restrict__ qv, u16* __restrict__ kbuf,
    u16* __restrict__ vtbuf, u16* __restrict__ rbuf, float* __restrict__ dout,
    const float* __restrict__ uvec, const float* __restrict__ vvec, int movr) {
  __shared__ __align__(16) u16 lA[64 * 64];
  __shared__ __align__(16) u16 lB[64 * 64];
  const int mode = (movr >= 0) ? movr : (int)blockIdx.z;
  const u16* A = (mode == 3) ? relbf : ((mode == 4) ? obf : xbf);
  const u16* Wm = wt5 + (size_t)mode * 1048576;
  const int tid = threadIdx.x;
  const int lane = tid & 63, gq = lane >> 4, cl = lane & 15;
  const int wv = tid >> 6, wm = wv >> 1, wn = wv & 1;
  const int by = blockIdx.y * 64, bx = blockIdx.x * 64;
  const f32x4 fz = {0.f, 0.f, 0.f, 0.f};

  f32x4 acc[2][2];
#pragma unroll
  for (int a = 0; a < 2; ++a)
#pragma unroll
    for (int bq = 0; bq < 2; ++bq) acc[a][bq] = fz;

  const int off0 = tid * 16, off1 = tid * 16 + 4096;
  const int L0 = off0 ^ (((off0 >> 7) & 7) << 4);
  const int L1 = off1 ^ (((off1 >> 7) & 7) << 4);
  const int rr0 = off0 >> 7, ke0 = (L0 & 127) >> 1;
  const int rr1 = off1 >> 7, ke1 = (L1 & 127) >> 1;
  const u16* pA0 = A + (size_t)(by + rr0) * 1024 + ke0;
  const u16* pA1 = A + (size_t)(by + rr1) * 1024 + ke1;
  const u16* pB0 = Wm + (size_t)(bx + rr0) * 1024 + ke0;
  const u16* pB1 = Wm + (size_t)(bx + rr1) * 1024 + ke1;

  for (int k0 = 0; k0 < 1024; k0 += 64) {
    gll16(pA0 + k0, (char*)lA + off0);
    gll16(pA1 + k0, (char*)lA + off1);
    gll16(pB0 + k0, (char*)lB + off0);
    gll16(pB1 + k0, (char*)lB + off1);
    __syncthreads();
    bf16x8 af[2][2], bff[2][2];
#pragma unroll
    for (int mi = 0; mi < 2; ++mi)
#pragma unroll
      for (int kb = 0; kb < 2; ++kb) {
        int row = wm * 32 + mi * 16 + cl;
        int byte = row * 128 + kb * 64 + gq * 16;
        byte ^= ((row & 7) << 4);
        af[mi][kb] = *(const bf16x8*)((const char*)lA + byte);
      }
#pragma unroll
    for (int ni = 0; ni < 2; ++ni)
#pragma unroll
      for (int kb = 0; kb < 2; ++kb) {
        int row = wn * 32 + ni * 16 + cl;
        int byte = row * 128 + kb * 64 + gq * 16;
        byte ^= ((row & 7) << 4);
        bff[ni][kb] = *(const bf16x8*)((const char*)lB + byte);
      }
#pragma unroll
    for (int mi = 0; mi < 2; ++mi)
#pragma unroll
      for (int ni = 0; ni < 2; ++ni) {
        acc[mi][ni] = mfma16x16x32(af[mi][0], bff[ni][0], acc[mi][ni]);
        acc[mi][ni] = mfma16x16x32(af[mi][1], bff[ni][1], acc[mi][ni]);
      }
    __syncthreads();
  }

#pragma unroll
  for (int mi = 0; mi < 2; ++mi)
#pragma unroll
    for (int ni = 0; ni < 2; ++ni) {
      int n = bx + wn * 32 + ni * 16 + cl;
      float ub = 0.f, vb = 0.f;
      if (mode == 0) { ub = uvec[n]; vb = vvec[n]; }
#pragma unroll
      for (int r = 0; r < 4; ++r) {
        int m = by + wm * 32 + mi * 16 + 4 * gq + r;
        float val = acc[mi][ni][r];
        if (mode == 0) {
          // softmax scale (1/8) folded in here
          qu[(size_t)m * 1024 + n] = f2bf((val + ub) * 0.125f);
          qv[(size_t)m * 1024 + n] = f2bf((val + vb) * 0.125f);
        } else if (mode == 1) {
          dout[2097152 + (size_t)m * 1024 + n] = val;
          kbuf[(((size_t)((m >> 10) * 16 + (n >> 6))) * 2048 + 1024 + (m & 1023)) * 64 +
               (n & 63)] = f2bf(val);
        } else if (mode == 2) {
          dout[4194304 + (size_t)m * 1024 + n] = val;
          vtbuf[(((size_t)((m >> 10) * 16 + (n >> 6))) * 64 + (n & 63)) * 2048 + 1024 +
                (m & 1023)] = f2bf(val);
        } else if (mode == 3) {
          rbuf[((size_t)(n >> 6) * 2048 + m) * 64 + (n & 63)] = f2bf(val);
        } else {
          dout[(size_t)m * 1024 + n] = val;
        }
      }
    }
}

// --- flash attention, split-key, 1 wave / 16 q-rows per block ---------------
// grid x in [0,128) = chunk*64 + qt, y = h, z = b (XCD remap inside)
__global__ __launch_bounds__(64, 2) void attn_kernel(
    const u16* __restrict__ qu, const u16* __restrict__ qv,
    const u16* __restrict__ kbuf, const u16* __restrict__ vtbuf,
    const u16* __restrict__ rbuf, const int* __restrict__ qseg,
    const int* __restrict__ kseg, u16* __restrict__ pO,
    float* __restrict__ pml) {
  __shared__ __align__(16) u16 ldsP[16 * 64];  // 2KB, wave-private

  const int lane = threadIdx.x;
  const int gq = lane >> 4, cl = lane & 15;
  // XCD-locality remap (bijective over 4096): 4 (b,h) per XCD
  int lin = blockIdx.x + 128 * (blockIdx.y + 16 * blockIdx.z);
  lin = (lin & 7) * 512 + (lin >> 3);
  const int xx = lin & 127, bh = lin >> 7;
  const int chunk = xx >> 6, qt = xx & 63;
  const int b = bh >> 4, h = bh & 15;
  const int i0 = qt * 16;
  const int tmax = (i0 + 15 + 1024) >> 6;
  const f32x4 fz = {0.f, 0.f, 0.f, 0.f};

  const u16* Kb = kbuf + (size_t)bh * 2048 * 64;   // [s][d=64]
  const u16* Vb = vtbuf + (size_t)bh * 64 * 2048;  // [d][s=2048]
  const u16* rbh = rbuf + (size_t)h * 2048 * 64;   // [e][d=64]
  const int* ksegb = kseg + (size_t)b * 2048;

  // Q fragments (pre-scaled by 1/8): row=cl, k=32*kb+8*gq+j
  bf16x8 aU[2], aV[2];
#pragma unroll
  for (int kb = 0; kb < 2; ++kb) {
    size_t off = ((size_t)b * 1024 + i0 + cl) * 1024 + h * 64 + kb * 32 + gq * 8;
    aU[kb] = *(const bf16x8*)(qu + off);
    aV[kb] = *(const bf16x8*)(qv + off);
  }
  // loop-invariant per-row constants
  int qsv[4], srcl[4], athr[4];
  bool sel[4];
#pragma unroll
  for (int r = 0; r < 4; ++r) {
    int ri = 4 * gq + r;
    qsv[r] = qseg[b * 1024 + i0 + ri];
    int lc = cl - ri + 15;  // in [0,30]
    srcl[r] = (gq << 4) | (lc & 15);
    sel[r] = (lc < 16);
    athr[r] = i0 + ri + 1024 - cl;  // causal: j0t+16jt <= athr
  }

  float mrun[4], lrun[4];
  f32x4 oacc[4];
#pragma unroll
  for (int r = 0; r < 4; ++r) { mrun[r] = -1e30f; lrun[r] = 0.f; }
#pragma unroll
  for (int di = 0; di < 4; ++di) oacc[di] = fz;

  for (int t = chunk; t <= tmax; t += 2) {
    const int j0t = t * 64;
    const int Rb0 = j0t - i0 + 1008;  // 16-aligned band base, >= 0
    // ---- batch-issue ALL tile loads (K, R, V, kseg). The sched_barrier(0)
    // below makes all results live across it -> RA must keep ~26 loads in
    // flight together (one L2 round-trip per tile, not 26 serial). ----
    bf16x8 Kf[4][2];
#pragma unroll
    for (int jt = 0; jt < 4; ++jt) {
      const u16* kp = Kb + (size_t)(j0t + 16 * jt + cl) * 64 + gq * 8;
      Kf[jt][0] = *(const bf16x8*)kp;
      Kf[jt][1] = *(const bf16x8*)(kp + 32);
    }
    bf16x8 Rf[5][2];
#pragma unroll
    for (int p = 0; p < 5; ++p) {
      const u16* rp = rbh + (size_t)min(Rb0 + 16 * p + cl, 2047) * 64 + gq * 8;
      Rf[p][0] = *(const bf16x8*)rp;
      Rf[p][1] = *(const bf16x8*)(rp + 32);
    }
    bf16x8 Vf[4][2];
#pragma unroll
    for (int di = 0; di < 4; ++di) {
      const u16* vp = Vb + (size_t)(di * 16 + cl) * 2048 + j0t + gq * 8;
      Vf[di][0] = *(const bf16x8*)vp;
      Vf[di][1] = *(const bf16x8*)(vp + 32);
    }
    int ksv[4];
#pragma unroll
    for (int jt = 0; jt < 4; ++jt) ksv[jt] = ksegb[j0t + 16 * jt + cl];
    __builtin_amdgcn_sched_barrier(0);  // fence: no load sinks past here

    // ---- QK^T and bias-band MFMAs (bands shared: bd1[jt] == bd0[jt+1]) ----
    f32x4 xq[4];
#pragma unroll
    for (int jt = 0; jt < 4; ++jt) {
      f32x4 a = mfma16x16x32(aU[0], Kf[jt][0], fz);
      xq[jt] = mfma16x16x32(aU[1], Kf[jt][1], a);
    }
    f32x4 bb[5];
#pragma unroll
    for (int p = 0; p < 5; ++p) {
      f32x4 a = mfma16x16x32(aV[0], Rf[p][0], fz);
      bb[p] = mfma16x16x32(aV[1], Rf[p][1], a);
    }
    // ---- diagonal gather: 20 independent bpermutes, batch-issued ----
    float D[5][4];
#pragma unroll
    for (int p = 0; p < 5; ++p)
#pragma unroll
      for (int r = 0; r < 4; ++r) D[p][r] = __shfl(bb[p][r], srcl[r]);
    __builtin_amdgcn_sched_barrier(0);  // fence: gathers issue as one batch

    // ---- scores + mask ----
    float x[4][4];
#pragma unroll
    for (int jt = 0; jt < 4; ++jt)
#pragma unroll
      for (int r = 0; r < 4; ++r) {
        float bdv = sel[r] ? D[jt][r] : D[jt + 1][r];
        bool ok = (j0t + 16 * jt <= athr[r]) && (ksv[jt] == qsv[r]);
        x[jt][r] = ok ? (xq[jt][r] + bdv) : -1e30f;
      }

    // ---- online softmax (DPP allreduce, VALU pipe) ----
    char* Pm = (char*)ldsP;
    float alf[4];
#pragma unroll
    for (int r = 0; r < 4; ++r) {
      float mx = fmaxf(fmaxf(x[0][r], x[1][r]), fmaxf(x[2][r], x[3][r]));
      mx = dpp_max16(mx);
      float mold = mrun[r];
      float mnew = fmaxf(mold, mx);
      float al = __expf(mold - mnew);
      float p0 = __expf(x[0][r] - mnew);
      float p1 = __expf(x[1][r] - mnew);
      float p2 = __expf(x[2][r] - mnew);
      float p3 = __expf(x[3][r] - mnew);
      float s = dpp_sum16(p0 + p1 + p2 + p3);
      mrun[r] = mnew;
      lrun[r] = lrun[r] * al + s;
      alf[r] = al;
      int ri = 4 * gq + r;
      int bbx = (ri & 7) << 4;
      *(u16*)(Pm + ((ri * 128 + cl * 2) ^ bbx)) = f2bf(p0);
      *(u16*)(Pm + ((ri * 128 + (16 + cl) * 2) ^ bbx)) = f2bf(p1);
      *(u16*)(Pm + ((ri * 128 + (32 + cl) * 2) ^ bbx)) = f2bf(p2);
      *(u16*)(Pm + ((ri * 128 + (48 + cl) * 2) ^ bbx)) = f2bf(p3);
    }
    f32x4 av = {alf[0], alf[1], alf[2], alf[3]};
#pragma unroll
    for (int di = 0; di < 4; ++di) oacc[di] *= av;
    // ---- PV (P round-trip same-wave; V already in regs) ----
    int psw = (cl & 7) << 4;
    bf16x8 pf0 = *(const bf16x8*)(Pm + ((cl * 128 + gq * 16) ^ psw));
    bf16x8 pf1 = *(const bf16x8*)(Pm + ((cl * 128 + 64 + gq * 16) ^ psw));
#pragma unroll
    for (int di = 0; di < 4; ++di) {
      oacc[di] = mfma16x16x32(pf0, Vf[di][0], oacc[di]);
      oacc[di] = mfma16x16x32(pf1, Vf[di][1], oacc[di]);
    }
  }

  // epilogue: raw partials (no 1/l) + (m,l)
#pragma unroll
  for (int r = 0; r < 4; ++r) {
    int iq = i0 + 4 * gq + r;
    size_t rowp = ((size_t)bh * 2 + chunk) * 1024 + iq;
#pragma unroll
    for (int di = 0; di < 4; ++di)
      pO[rowp * 64 + di * 16 + cl] = f2bf(oacc[di][r]);
    if (cl == 0) {
      pml[rowp * 2] = mrun[r];
      pml[rowp * 2 + 1] = lrun[r];
    }
  }
}

// --- split-key combine -------------------------------------------------------
__global__ __launch_bounds__(256) void combine_kernel(
    const u16* __restrict__ pO, const float* __restrict__ pml,
    u16* __restrict__ obf) {
  int gid = blockIdx.x * 256 + threadIdx.x;  // 262144
  int d8 = (gid & 7) * 8;
  int row = gid >> 3;  // bh*1024 + iq
  int bh = row >> 10, iq = row & 1023;
  int b = bh >> 4, h = bh & 15;
  size_t r0 = ((size_t)bh * 2) * 1024 + iq;
  size_t r1 = r0 + 1024;
  float m0 = pml[r0 * 2], l0 = pml[r0 * 2 + 1];
  float m1 = pml[r1 * 2], l1 = pml[r1 * 2 + 1];
  float ms = fmaxf(m0, m1);
  float w0 = __expf(m0 - ms), w1 = __expf(m1 - ms);
  float inv = 1.0f / fmaxf(l0 * w0 + l1 * w1, 1e-30f);
  bf16x8 a = *(const bf16x8*)(pO + r0 * 64 + d8);
  bf16x8 c = *(const bf16x8*)(pO + r1 * 64 + d8);
  bf16x8 o;
#pragma unroll
  for (int j = 0; j < 8; ++j) {
    float f = (bf2f((u16)a[j]) * w0 + bf2f((u16)c[j]) * w1) * inv;
    o[j] = (short)f2bf(f);
  }
  *(bf16x8*)(obf + ((size_t)b * 1024 + iq) * 1024 + h * 64 + d8) = o;
}

// ---------------------------------------------------------------------------
extern "C" void kernel_launch(void* const* d_in, const int* in_sizes, int n_in,
                              void* d_out, int out_size, void* d_ws, size_t ws_size,
                              hipStream_t stream) {
  (void)in_sizes; (void)n_in; (void)out_size; (void)ws_size;
  const float* x           = (const float*)d_in[0];
  const int*   mask        = (const int*)d_in[1];
  const int*   mem_mask    = (const int*)d_in[3];
  const float* cache_key   = (const float*)d_in[4];
  const float* cache_value = (const float*)d_in[5];
  const int*   cache_mask  = (const int*)d_in[6];
  const float* rel_emb     = (const float*)d_in[7];
  const float* Wq          = (const float*)d_in[8];
  const float* Wk          = (const float*)d_in[9];
  const float* Wv          = (const float*)d_in[10];
  const float* Wr          = (const float*)d_in[11];
  const float* uvec        = (const float*)d_in[12];
  const float* vvec        = (const float*)d_in[13];
  const float* Wo          = (const float*)d_in[14];
  float* dout = (float*)d_out;

  char* W = (char*)d_ws;  // ~50.6 MB of workspace used
  u16* xbf   = (u16*)(W + (0u << 20));   // dead after projection GEMMs
  u16* relbf = (u16*)(W + (4u << 20));   // dead after projection GEMMs
  u16* pO    = (u16*)(W + (0u << 20));   // reuses xbf+relbf (8 MiB exactly)
  u16* wt5   = (u16*)(W + (8u << 20));
  u16* kbuf  = (u16*)(W + (18u << 20));
  u16* vtbuf = (u16*)(W + (26u << 20));
  u16* rbuf  = (u16*)(W + (34u << 20));
  u16* qu    = (u16*)(W + (38u << 20));
  u16* qv    = (u16*)(W + (42u << 20));
  u16* obf   = (u16*)(W + (46u << 20));
  int* qseg  = (int*)(W + (50u << 20));
  int* kseg  = (int*)(W + (50u << 20) + 8192);
  float* pml = (float*)(W + (50u << 20) + 32768);

  seg_scan_kernel<<<dim3(2), dim3(64), 0, stream>>>(mask, mem_mask, cache_mask, qseg, kseg);
  cvt_bf16_kernel<<<dim3(2048), dim3(256), 0, stream>>>(x, xbf, 2097152);
  cvt_bf16_kernel<<<dim3(2048), dim3(256), 0, stream>>>(rel_emb, relbf, 2097152);
  tr_w_kernel<<<dim3(32, 32), dim3(256), 0, stream>>>(Wq, wt5);
  tr_w_kernel<<<dim3(32, 32), dim3(256), 0, stream>>>(Wk, wt5 + (1u << 20));
  tr_w_kernel<<<dim3(32, 32), dim3(256), 0, stream>>>(Wv, wt5 + (2u << 20));
  tr_w_kernel<<<dim3(32, 32), dim3(256), 0, stream>>>(Wr, wt5 + (3u << 20));
  tr_w_kernel<<<dim3(32, 32), dim3(256), 0, stream>>>(Wo, wt5 + (4u << 20));
  ck_perm_kernel<<<dim3(2048), dim3(256), 0, stream>>>(cache_key, kbuf);
  cv_tr_kernel<<<dim3(32, 2, 32), dim3(256), 0, stream>>>(cache_value, vtbuf);
  gemm_proj_kernel<<<dim3(16, 32, 4), dim3(256), 0, stream>>>(
      xbf, relbf, obf, wt5, qu, qv, kbuf, vtbuf, rbuf, dout, uvec, vvec, -1);
  attn_kernel<<<dim3(128, 16, 2), dim3(64), 0, stream>>>(qu, qv, kbuf, vtbuf, rbuf,
                                                         qseg, kseg, pO, pml);
  combine_kernel<<<dim3(1024), dim3(256), 0, stream>>>(pO, pml, obf);
  gemm_proj_kernel<<<dim3(16, 32, 1), dim3(256), 0, stream>>>(
      xbf, relbf, obf, wt5, qu, qv, kbuf, vtbuf, rbuf, dout, uvec, vvec, 4);
}

// Round 8
// 264.545 us; speedup vs baseline: 1.6724x; 1.0243x over previous
//
#include <hip/hip_runtime.h>
#include <hip/hip_bf16.h>
#include <climits>

// ---------------------------------------------------------------------------
// RelativeMultiHeadAttentionBlock (Transformer-XL style) on MI355X (gfx950)
// B=2, T=C=1024, M=1024, S=2048, H=16, HD=64, F=1024. fp32 in/out, bf16 MFMA.
//
// R7: R6 body kept (batched loads + sched_barrier fences + DPP softmax +
// band-shared bias). Three changes:
//  - 4-way key split: 8192 one-wave blocks -> 32 waves/CU assigned (queue
//    depth covers stalls+tail; R6 had only 16).
//  - NON-TEMPORAL pO/pml stores: R3's 4-way attempt thrashed L2 with 16MB of
//    allocating partial writes (FETCH 388MB); nt stores protect the read set.
//  - VALU trims: HW bf16 cvt (__float2bfloat16) and exp2-domain softmax
//    (0.125*log2e folded into q projection; exp2f everywhere incl. combine).
// ---------------------------------------------------------------------------

typedef unsigned short u16;
typedef short bf16x8 __attribute__((ext_vector_type(8)));
typedef float f32x4 __attribute__((ext_vector_type(4)));

__device__ __forceinline__ f32x4 mfma16x16x32(bf16x8 a, bf16x8 b, f32x4 c) {
  return __builtin_amdgcn_mfma_f32_16x16x32_bf16(a, b, c, 0, 0, 0);
}

__device__ __forceinline__ u16 f2bf(float f) {  // RNE via HW cvt
  __hip_bfloat16 h = __float2bfloat16(f);
  return *reinterpret_cast<u16*>(&h);
}

__device__ __forceinline__ float bf2f(u16 x) {
  unsigned u = ((unsigned)x) << 16;
  return __builtin_bit_cast(float, u);
}

__device__ __forceinline__ void gll16(const void* g, void* l) {
  __builtin_amdgcn_global_load_lds(
      (const __attribute__((address_space(1))) void*)g,
      (__attribute__((address_space(3))) void*)l, 16, 0, 0);
}

// DPP 16-lane rotation allreduce (VALU pipe; rows of 16 = our gq groups)
template <int CTRL>
__device__ __forceinline__ float rot16(float x) {
  int i = __builtin_bit_cast(int, x);
  int r = __builtin_amdgcn_update_dpp(i, i, CTRL, 0xF, 0xF, false);
  return __builtin_bit_cast(float, r);
}
__device__ __forceinline__ float dpp_max16(float x) {
  x = fmaxf(x, rot16<0x128>(x));  // ror:8
  x = fmaxf(x, rot16<0x124>(x));  // ror:4
  x = fmaxf(x, rot16<0x122>(x));  // ror:2
  x = fmaxf(x, rot16<0x121>(x));  // ror:1
  return x;
}
__device__ __forceinline__ float dpp_sum16(float x) {
  x += rot16<0x128>(x);
  x += rot16<0x124>(x);
  x += rot16<0x122>(x);
  x += rot16<0x121>(x);
  return x;
}

// --- segment ids ------------------------------------------------------------
__global__ __launch_bounds__(64) void seg_scan_kernel(
    const int* __restrict__ mask, const int* __restrict__ mem_mask,
    const int* __restrict__ cache_mask, int* __restrict__ qseg,
    int* __restrict__ kseg) {
  __shared__ int cs[3072];
  int b = blockIdx.x, lane = threadIdx.x;
  int carry = 0;
  for (int base = 0; base < 3072; base += 64) {
    int idx = base + lane;
    int val;
    if (idx < 1024)      val = mem_mask[b * 1024 + idx];
    else if (idx < 2048) val = cache_mask[b * 1024 + idx - 1024];
    else                 val = mask[b * 1024 + idx - 2048];
    for (int o = 1; o < 64; o <<= 1) {
      int n = __shfl_up(val, o);
      if (lane >= o) val += n;
    }
    val += carry;
    cs[idx] = val;
    carry = __shfl(val, 63);
  }
  __syncthreads();
  int mx = INT_MIN;
  for (int i = lane; i < 2048; i += 64) mx = max(mx, cs[i]);
  for (int o = 1; o < 64; o <<= 1) mx = max(mx, __shfl_xor(mx, o));
  int cs2047 = cs[2047];
  for (int t = lane; t < 1024; t += 64) qseg[b * 1024 + t] = cs[2048 + t] - cs2047 + mx;
  for (int j = lane; j < 2048; j += 64) kseg[b * 2048 + j] = cs[1024 + j];
}

// --- preps ------------------------------------------------------------------
__global__ __launch_bounds__(256) void cvt_bf16_kernel(const float* __restrict__ src,
                                                       u16* __restrict__ dst, int n) {
  int i = (blockIdx.x * 256 + threadIdx.x) * 4;
  if (i >= n) return;
  float4 v = *(const float4*)(src + i);
  dst[i + 0] = f2bf(v.x); dst[i + 1] = f2bf(v.y);
  dst[i + 2] = f2bf(v.z); dst[i + 3] = f2bf(v.w);
}

__global__ __launch_bounds__(256) void tr_w_kernel(const float* __restrict__ src,
                                                   u16* __restrict__ dst) {
  __shared__ float tile[32][33];
  int tx = threadIdx.x & 31, ty = threadIdx.x >> 5;
  int r0 = blockIdx.y * 32, c0 = blockIdx.x * 32;
#pragma unroll
  for (int i = 0; i < 32; i += 8)
    tile[ty + i][tx] = src[(size_t)(r0 + ty + i) * 1024 + c0 + tx];
  __syncthreads();
#pragma unroll
  for (int i = 0; i < 32; i += 8)
    dst[(size_t)(c0 + ty + i) * 1024 + r0 + tx] = f2bf(tile[tx][ty + i]);
}

__global__ __launch_bounds__(256) void ck_perm_kernel(const float* __restrict__ src,
                                                      u16* __restrict__ dst) {
  int i = blockIdx.x * 256 + threadIdx.x;  // 524288 quads
  int dq = i & 15, h = (i >> 4) & 15, t = (i >> 8) & 1023, b = i >> 18;
  float4 v = *(const float4*)(src + (size_t)i * 4);
  size_t o = (((size_t)(b * 16 + h)) * 2048 + t) * 64 + dq * 4;
  dst[o + 0] = f2bf(v.x); dst[o + 1] = f2bf(v.y);
  dst[o + 2] = f2bf(v.z); dst[o + 3] = f2bf(v.w);
}

__global__ __launch_bounds__(256) void cv_tr_kernel(const float* __restrict__ src,
                                                    u16* __restrict__ dst) {
  __shared__ float tile[32][33];
  int bh = blockIdx.z, b = bh >> 4, h = bh & 15;
  int t0 = blockIdx.x * 32, d0 = blockIdx.y * 32;
  int tx = threadIdx.x & 31, ty = threadIdx.x >> 5;
#pragma unroll
  for (int i = 0; i < 32; i += 8)
    tile[ty + i][tx] = src[(((size_t)b * 1024 + t0 + ty + i) * 16 + h) * 64 + d0 + tx];
  __syncthreads();
#pragma unroll
  for (int i = 0; i < 32; i += 8)
    dst[((size_t)bh * 64 + d0 + ty + i) * 2048 + t0 + tx] = f2bf(tile[tx][ty + i]);
}

// --- projection / output GEMM ----------------------------------------------
__global__ __launch_bounds__(256) void gemm_proj_kernel(
    const u16* __restrict__ xbf, const u16* __restrict__ relbf,
    const u16* __restrict__ obf, const u16* __restrict__ wt5,
    u16* __restrict__ qu, u16* __restrict__ qv, u16* __restrict__ kbuf,
    u16* __restrict__ vtbuf, u16* __restrict__ rbuf, float* __restrict__ dout,
    const float* __restrict__ uvec, const float* __restrict__ vvec, int movr) {
  __shared__ __align__(16) u16 lA[64 * 64];
  __shared__ __align__(16) u16 lB[64 * 64];
  const int mode = (movr >= 0) ? movr : (int)blockIdx.z;
  const u16* A = (mode == 3) ? relbf : ((mode == 4) ? obf : xbf);
  const u16* Wm = wt5 + (size_t)mode * 1048576;
  const int tid = threadIdx.x;
  const int lane = tid & 63, gq = lane >> 4, cl = lane & 15;
  const int wv = tid >> 6, wm = wv >> 1, wn = wv & 1;
  const int by = blockIdx.y * 64, bx = blockIdx.x * 64;
  const f32x4 fz = {0.f, 0.f, 0.f, 0.f};

  f32x4 acc[2][2];
#pragma unroll
  for (int a = 0; a < 2; ++a)
#pragma unroll
    for (int bq = 0; bq < 2; ++bq) acc[a][bq] = fz;

  const int off0 = tid * 16, off1 = tid * 16 + 4096;
  const int L0 = off0 ^ (((off0 >> 7) & 7) << 4);
  const int L1 = off1 ^ (((off1 >> 7) & 7) << 4);
  const int rr0 = off0 >> 7, ke0 = (L0 & 127) >> 1;
  const int rr1 = off1 >> 7, ke1 = (L1 & 127) >> 1;
  const u16* pA0 = A + (size_t)(by + rr0) * 1024 + ke0;
  const u16* pA1 = A + (size_t)(by + rr1) * 1024 + ke1;
  const u16* pB0 = Wm + (size_t)(bx + rr0) * 1024 + ke0;
  const u16* pB1 = Wm + (size_t)(bx + rr1) * 1024 + ke1;

  for (int k0 = 0; k0 < 1024; k0 += 64) {
    gll16(pA0 + k0, (char*)lA + off0);
    gll16(pA1 + k0, (char*)lA + off1);
    gll16(pB0 + k0, (char*)lB + off0);
    gll16(pB1 + k0, (char*)lB + off1);
    __syncthreads();
    bf16x8 af[2][2], bff[2][2];
#pragma unroll
    for (int mi = 0; mi < 2; ++mi)
#pragma unroll
      for (int kb = 0; kb < 2; ++kb) {
        int row = wm * 32 + mi * 16 + cl;
        int byte = row * 128 + kb * 64 + gq * 16;
        byte ^= ((row & 7) << 4);
        af[mi][kb] = *(const bf16x8*)((const char*)lA + byte);
      }
#pragma unroll
    for (int ni = 0; ni < 2; ++ni)
#pragma unroll
      for (int kb = 0; kb < 2; ++kb) {
        int row = wn * 32 + ni * 16 + cl;
        int byte = row * 128 + kb * 64 + gq * 16;
        byte ^= ((row & 7) << 4);
        bff[ni][kb] = *(const bf16x8*)((const char*)lB + byte);
      }
#pragma unroll
    for (int mi = 0; mi < 2; ++mi)
#pragma unroll
      for (int ni = 0; ni < 2; ++ni) {
        acc[mi][ni] = mfma16x16x32(af[mi][0], bff[ni][0], acc[mi][ni]);
        acc[mi][ni] = mfma16x16x32(af[mi][1], bff[ni][1], acc[mi][ni]);
      }
    __syncthreads();
  }

  // 0.125 (softmax scale) * log2(e) -> exp2-domain logits downstream
  const float SC = 0.18033688011112042f;
#pragma unroll
  for (int mi = 0; mi < 2; ++mi)
#pragma unroll
    for (int ni = 0; ni < 2; ++ni) {
      int n = bx + wn * 32 + ni * 16 + cl;
      float ub = 0.f, vb = 0.f;
      if (mode == 0) { ub = uvec[n]; vb = vvec[n]; }
#pragma unroll
      for (int r = 0; r < 4; ++r) {
        int m = by + wm * 32 + mi * 16 + 4 * gq + r;
        float val = acc[mi][ni][r];
        if (mode == 0) {
          qu[(size_t)m * 1024 + n] = f2bf((val + ub) * SC);
          qv[(size_t)m * 1024 + n] = f2bf((val + vb) * SC);
        } else if (mode == 1) {
          dout[2097152 + (size_t)m * 1024 + n] = val;
          kbuf[(((size_t)((m >> 10) * 16 + (n >> 6))) * 2048 + 1024 + (m & 1023)) * 64 +
               (n & 63)] = f2bf(val);
        } else if (mode == 2) {
          dout[4194304 + (size_t)m * 1024 + n] = val;
          vtbuf[(((size_t)((m >> 10) * 16 + (n >> 6))) * 64 + (n & 63)) * 2048 + 1024 +
                (m & 1023)] = f2bf(val);
        } else if (mode == 3) {
          rbuf[((size_t)(n >> 6) * 2048 + m) * 64 + (n & 63)] = f2bf(val);
        } else {
          dout[(size_t)m * 1024 + n] = val;
        }
      }
    }
}

// --- flash attention, 4-way split-key, 1 wave / 16 q-rows per block ---------
// grid x in [0,256) = chunk*64 + qt, y = h, z = b (XCD remap inside)
__global__ __launch_bounds__(64, 2) void attn_kernel(
    const u16* __restrict__ qu, const u16* __restrict__ qv,
    const u16* __restrict__ kbuf, const u16* __restrict__ vtbuf,
    const u16* __restrict__ rbuf, const int* __restrict__ qseg,
    const int* __restrict__ kseg, u16* __restrict__ pO,
    float* __restrict__ pml) {
  __shared__ __align__(16) u16 ldsP[16 * 64];  // 2KB, wave-private

  const int lane = threadIdx.x;
  const int gq = lane >> 4, cl = lane & 15;
  // XCD-locality remap (bijective over 8192): 4 (b,h) per XCD
  int lin = blockIdx.x + 256 * (blockIdx.y + 16 * blockIdx.z);
  lin = (lin & 7) * 1024 + (lin >> 3);
  const int xx = lin & 255, bh = lin >> 8;
  const int chunk = xx >> 6, qt = xx & 63;
  const int b = bh >> 4, h = bh & 15;
  const int i0 = qt * 16;
  const int tmax = (i0 + 15 + 1024) >> 6;
  const f32x4 fz = {0.f, 0.f, 0.f, 0.f};

  const u16* Kb = kbuf + (size_t)bh * 2048 * 64;   // [s][d=64]
  const u16* Vb = vtbuf + (size_t)bh * 64 * 2048;  // [d][s=2048]
  const u16* rbh = rbuf + (size_t)h * 2048 * 64;   // [e][d=64]
  const int* ksegb = kseg + (size_t)b * 2048;

  // Q fragments (pre-scaled by 0.125*log2e): row=cl, k=32*kb+8*gq+j
  bf16x8 aU[2], aV[2];
#pragma unroll
  for (int kb = 0; kb < 2; ++kb) {
    size_t off = ((size_t)b * 1024 + i0 + cl) * 1024 + h * 64 + kb * 32 + gq * 8;
    aU[kb] = *(const bf16x8*)(qu + off);
    aV[kb] = *(const bf16x8*)(qv + off);
  }
  // loop-invariant per-row constants
  int qsv[4], srcl[4], athr[4];
  bool sel[4];
#pragma unroll
  for (int r = 0; r < 4; ++r) {
    int ri = 4 * gq + r;
    qsv[r] = qseg[b * 1024 + i0 + ri];
    int lc = cl - ri + 15;  // in [0,30]
    srcl[r] = (gq << 4) | (lc & 15);
    sel[r] = (lc < 16);
    athr[r] = i0 + ri + 1024 - cl;  // causal: j0t+16jt <= athr
  }

  float mrun[4], lrun[4];
  f32x4 oacc[4];
#pragma unroll
  for (int r = 0; r < 4; ++r) { mrun[r] = -1e30f; lrun[r] = 0.f; }
#pragma unroll
  for (int di = 0; di < 4; ++di) oacc[di] = fz;

  for (int t = chunk; t <= tmax; t += 4) {
    const int j0t = t * 64;
    const int Rb0 = j0t - i0 + 1008;  // 16-aligned band base, >= 0
    // ---- batch-issue ALL tile loads (K, R, V, kseg); fence keeps them
    // live-across -> RA must hold ~26 loads in flight (one L2 round-trip) ----
    bf16x8 Kf[4][2];
#pragma unroll
    for (int jt = 0; jt < 4; ++jt) {
      const u16* kp = Kb + (size_t)(j0t + 16 * jt + cl) * 64 + gq * 8;
      Kf[jt][0] = *(const bf16x8*)kp;
      Kf[jt][1] = *(const bf16x8*)(kp + 32);
    }
    bf16x8 Rf[5][2];
#pragma unroll
    for (int p = 0; p < 5; ++p) {
      const u16* rp = rbh + (size_t)min(Rb0 + 16 * p + cl, 2047) * 64 + gq * 8;
      Rf[p][0] = *(const bf16x8*)rp;
      Rf[p][1] = *(const bf16x8*)(rp + 32);
    }
    bf16x8 Vf[4][2];
#pragma unroll
    for (int di = 0; di < 4; ++di) {
      const u16* vp = Vb + (size_t)(di * 16 + cl) * 2048 + j0t + gq * 8;
      Vf[di][0] = *(const bf16x8*)vp;
      Vf[di][1] = *(const bf16x8*)(vp + 32);
    }
    int ksv[4];
#pragma unroll
    for (int jt = 0; jt < 4; ++jt) ksv[jt] = ksegb[j0t + 16 * jt + cl];
    __builtin_amdgcn_sched_barrier(0);  // fence: no load sinks past here

    // ---- QK^T and bias-band MFMAs (bands shared: bd1[jt] == bd0[jt+1]) ----
    f32x4 xq[4];
#pragma unroll
    for (int jt = 0; jt < 4; ++jt) {
      f32x4 a = mfma16x16x32(aU[0], Kf[jt][0], fz);
      xq[jt] = mfma16x16x32(aU[1], Kf[jt][1], a);
    }
    f32x4 bb[5];
#pragma unroll
    for (int p = 0; p < 5; ++p) {
      f32x4 a = mfma16x16x32(aV[0], Rf[p][0], fz);
      bb[p] = mfma16x16x32(aV[1], Rf[p][1], a);
    }
    // ---- diagonal gather: 20 independent bpermutes, batch-issued ----
    float D[5][4];
#pragma unroll
    for (int p = 0; p < 5; ++p)
#pragma unroll
      for (int r = 0; r < 4; ++r) D[p][r] = __shfl(bb[p][r], srcl[r]);
    __builtin_amdgcn_sched_barrier(0);  // fence: gathers issue as one batch

    // ---- scores + mask (exp2 domain) ----
    float x[4][4];
#pragma unroll
    for (int jt = 0; jt < 4; ++jt)
#pragma unroll
      for (int r = 0; r < 4; ++r) {
        float bdv = sel[r] ? D[jt][r] : D[jt + 1][r];
        bool ok = (j0t + 16 * jt <= athr[r]) && (ksv[jt] == qsv[r]);
        x[jt][r] = ok ? (xq[jt][r] + bdv) : -1e30f;
      }

    // ---- online softmax (DPP allreduce; exp2) ----
    char* Pm = (char*)ldsP;
    float alf[4];
#pragma unroll
    for (int r = 0; r < 4; ++r) {
      float mx = fmaxf(fmaxf(x[0][r], x[1][r]), fmaxf(x[2][r], x[3][r]));
      mx = dpp_max16(mx);
      float mold = mrun[r];
      float mnew = fmaxf(mold, mx);
      float al = exp2f(mold - mnew);
      float p0 = exp2f(x[0][r] - mnew);
      float p1 = exp2f(x[1][r] - mnew);
      float p2 = exp2f(x[2][r] - mnew);
      float p3 = exp2f(x[3][r] - mnew);
      float s = dpp_sum16(p0 + p1 + p2 + p3);
      mrun[r] = mnew;
      lrun[r] = lrun[r] * al + s;
      alf[r] = al;
      int ri = 4 * gq + r;
      int bbx = (ri & 7) << 4;
      *(u16*)(Pm + ((ri * 128 + cl * 2) ^ bbx)) = f2bf(p0);
      *(u16*)(Pm + ((ri * 128 + (16 + cl) * 2) ^ bbx)) = f2bf(p1);
      *(u16*)(Pm + ((ri * 128 + (32 + cl) * 2) ^ bbx)) = f2bf(p2);
      *(u16*)(Pm + ((ri * 128 + (48 + cl) * 2) ^ bbx)) = f2bf(p3);
    }
    f32x4 av = {alf[0], alf[1], alf[2], alf[3]};
#pragma unroll
    for (int di = 0; di < 4; ++di) oacc[di] *= av;
    // ---- PV (P round-trip same-wave; V already in regs) ----
    int psw = (cl & 7) << 4;
    bf16x8 pf0 = *(const bf16x8*)(Pm + ((cl * 128 + gq * 16) ^ psw));
    bf16x8 pf1 = *(const bf16x8*)(Pm + ((cl * 128 + 64 + gq * 16) ^ psw));
#pragma unroll
    for (int di = 0; di < 4; ++di) {
      oacc[di] = mfma16x16x32(pf0, Vf[di][0], oacc[di]);
      oacc[di] = mfma16x16x32(pf1, Vf[di][1], oacc[di]);
    }
  }

  // epilogue: raw partials (no 1/l) + (m,l); non-temporal (protect L2 reads)
#pragma unroll
  for (int r = 0; r < 4; ++r) {
    int iq = i0 + 4 * gq + r;
    size_t rowp = ((size_t)bh * 4 + chunk) * 1024 + iq;
#pragma unroll
    for (int di = 0; di < 4; ++di)
      __builtin_nontemporal_store(f2bf(oacc[di][r]), &pO[rowp * 64 + di * 16 + cl]);
    if (cl == 0) {
      __builtin_nontemporal_store(mrun[r], &pml[rowp * 2]);
      __builtin_nontemporal_store(lrun[r], &pml[rowp * 2 + 1]);
    }
  }
}

// --- split-key combine (4 chunks, exp2 domain) ------------------------------
__global__ __launch_bounds__(256) void combine_kernel(
    const u16* __restrict__ pO, const float* __restrict__ pml,
    u16* __restrict__ obf) {
  int gid = blockIdx.x * 256 + threadIdx.x;  // 262144
  int d8 = (gid & 7) * 8;
  int row = gid >> 3;  // bh*1024 + iq
  int bh = row >> 10, iq = row & 1023;
  int b = bh >> 4, h = bh & 15;
  size_t rbase = (size_t)bh * 4 * 1024 + iq;
  float m[4], l[4], w[4];
  float ms = -1e30f;
#pragma unroll
  for (int c = 0; c < 4; ++c) {
    m[c] = pml[(rbase + c * 1024) * 2];
    l[c] = pml[(rbase + c * 1024) * 2 + 1];
    ms = fmaxf(ms, m[c]);
  }
  float den = 0.f;
#pragma unroll
  for (int c = 0; c < 4; ++c) { w[c] = exp2f(m[c] - ms); den += l[c] * w[c]; }
  float inv = 1.0f / fmaxf(den, 1e-30f);
  float acc[8] = {0, 0, 0, 0, 0, 0, 0, 0};
#pragma unroll
  for (int c = 0; c < 4; ++c) {
    bf16x8 a = *(const bf16x8*)(pO + (rbase + c * 1024) * 64 + d8);
#pragma unroll
    for (int j = 0; j < 8; ++j) acc[j] += bf2f((u16)a[j]) * w[c];
  }
  bf16x8 o;
#pragma unroll
  for (int j = 0; j < 8; ++j) o[j] = (short)f2bf(acc[j] * inv);
  *(bf16x8*)(obf + ((size_t)b * 1024 + iq) * 1024 + h * 64 + d8) = o;
}

// ---------------------------------------------------------------------------
extern "C" void kernel_launch(void* const* d_in, const int* in_sizes, int n_in,
                              void* d_out, int out_size, void* d_ws, size_t ws_size,
                              hipStream_t stream) {
  (void)in_sizes; (void)n_in; (void)out_size; (void)ws_size;
  const float* x           = (const float*)d_in[0];
  const int*   mask        = (const int*)d_in[1];
  const int*   mem_mask    = (const int*)d_in[3];
  const float* cache_key   = (const float*)d_in[4];
  const float* cache_value = (const float*)d_in[5];
  const int*   cache_mask  = (const int*)d_in[6];
  const float* rel_emb     = (const float*)d_in[7];
  const float* Wq          = (const float*)d_in[8];
  const float* Wk          = (const float*)d_in[9];
  const float* Wv          = (const float*)d_in[10];
  const float* Wr          = (const float*)d_in[11];
  const float* uvec        = (const float*)d_in[12];
  const float* vvec        = (const float*)d_in[13];
  const float* Wo          = (const float*)d_in[14];
  float* dout = (float*)d_out;

  char* W = (char*)d_ws;  // ~51.1 MB of workspace used
  u16* xbf   = (u16*)(W + (0u << 20));   // dead after projection GEMMs
  u16* relbf = (u16*)(W + (4u << 20));   // dead after projection GEMMs
  u16* pO    = (u16*)(W + (0u << 20));   // 16MB: overlays xbf,relbf,qkvr wts
  u16* wt5   = (u16*)(W + (8u << 20));   // q,k,v,r dead by attn; o at +8MB
  u16* kbuf  = (u16*)(W + (18u << 20));
  u16* vtbuf = (u16*)(W + (26u << 20));
  u16* rbuf  = (u16*)(W + (34u << 20));
  u16* qu    = (u16*)(W + (38u << 20));
  u16* qv    = (u16*)(W + (42u << 20));
  u16* obf   = (u16*)(W + (46u << 20));
  int* qseg  = (int*)(W + (50u << 20));
  int* kseg  = (int*)(W + (50u << 20) + 8192);
  float* pml = (float*)(W + (50u << 20) + 32768);

  seg_scan_kernel<<<dim3(2), dim3(64), 0, stream>>>(mask, mem_mask, cache_mask, qseg, kseg);
  cvt_bf16_kernel<<<dim3(2048), dim3(256), 0, stream>>>(x, xbf, 2097152);
  cvt_bf16_kernel<<<dim3(2048), dim3(256), 0, stream>>>(rel_emb, relbf, 2097152);
  tr_w_kernel<<<dim3(32, 32), dim3(256), 0, stream>>>(Wq, wt5);
  tr_w_kernel<<<dim3(32, 32), dim3(256), 0, stream>>>(Wk, wt5 + (1u << 20));
  tr_w_kernel<<<dim3(32, 32), dim3(256), 0, stream>>>(Wv, wt5 + (2u << 20));
  tr_w_kernel<<<dim3(32, 32), dim3(256), 0, stream>>>(Wr, wt5 + (3u << 20));
  tr_w_kernel<<<dim3(32, 32), dim3(256), 0, stream>>>(Wo, wt5 + (4u << 20));
  ck_perm_kernel<<<dim3(2048), dim3(256), 0, stream>>>(cache_key, kbuf);
  cv_tr_kernel<<<dim3(32, 2, 32), dim3(256), 0, stream>>>(cache_value, vtbuf);
  gemm_proj_kernel<<<dim3(16, 32, 4), dim3(256), 0, stream>>>(
      xbf, relbf, obf, wt5, qu, qv, kbuf, vtbuf, rbuf, dout, uvec, vvec, -1);
  attn_kernel<<<dim3(256, 16, 2), dim3(64), 0, stream>>>(qu, qv, kbuf, vtbuf, rbuf,
                                                         qseg, kseg, pO, pml);
  combine_kernel<<<dim3(1024), dim3(256), 0, stream>>>(pO, pml, obf);
  gemm_proj_kernel<<<dim3(16, 32, 1), dim3(256), 0, stream>>>(
      xbf, relbf, obf, wt5, qu, qv, kbuf, vtbuf, rbuf, dout, uvec, vvec, 4);
}